// Round 1
// baseline (1900.133 us; speedup 1.0000x reference)
//
#include <hip/hip_runtime.h>
#include <hip/hip_bf16.h>

#define HID 64
#define NEG_SLOPE 0.2f

// ---- order-preserving float <-> uint encoding for atomicMax on floats ----
__device__ __forceinline__ unsigned enc_f32(float f) {
    unsigned u = __float_as_uint(f);
    return (u & 0x80000000u) ? ~u : (u | 0x80000000u);
}
__device__ __forceinline__ float dec_f32(unsigned u) {
    unsigned b = (u & 0x80000000u) ? (u & 0x7FFFFFFFu) : ~u;
    return __uint_as_float(b);
}

// degree counts via atomics
__global__ void k_deg(const int* __restrict__ src, const int* __restrict__ dst,
                      float* deg_in, float* deg_out, int E) {
    int i = blockIdx.x * blockDim.x + threadIdx.x;
    if (i < E) {
        atomicAdd(&deg_out[src[i]], 1.0f);
        atomicAdd(&deg_in[dst[i]], 1.0f);
    }
}

// layer-1 transforms: h = [x, deg_in, deg_out] (N,3); xl = h@Wl+bl, xr = h@Wr+br
__global__ void k_xfrm1(const float* __restrict__ x, const float* __restrict__ deg_in,
                        const float* __restrict__ deg_out,
                        const float* __restrict__ Wl, const float* __restrict__ bl,
                        const float* __restrict__ Wr, const float* __restrict__ br,
                        float* __restrict__ A, float* __restrict__ B, int N) {
    int idx = blockIdx.x * blockDim.x + threadIdx.x;
    if (idx >= N * HID) return;
    int n = idx >> 6, c = idx & 63;
    float h0 = x[n], h1 = deg_in[n], h2 = deg_out[n];
    A[idx] = h0 * Wl[c] + h1 * Wl[HID + c] + h2 * Wl[2 * HID + c] + bl[c];
    B[idx] = h0 * Wr[c] + h1 * Wr[HID + c] + h2 * Wr[2 * HID + c] + br[c];
}

// per-edge attention logit e = a . leakyrelu(xl[s]+xr[d]); atomicMax into m[d]
// one wave (64 lanes) per edge; edges [0,E) real, [E,E+N) self loops
__global__ void k_logit(const int* __restrict__ src, const int* __restrict__ dst,
                        const float* __restrict__ A, const float* __restrict__ B,
                        const float* __restrict__ a,
                        float* __restrict__ e, unsigned* __restrict__ m, int E, int N) {
    int wid = (int)((blockIdx.x * (size_t)blockDim.x + threadIdx.x) >> 6);
    int lane = threadIdx.x & 63;
    int ET = E + N;
    if (wid >= ET) return;
    int s, d;
    if (wid < E) { s = src[wid]; d = dst[wid]; } else { s = d = wid - E; }
    float v = A[(size_t)s * HID + lane] + B[(size_t)d * HID + lane];
    v = v > 0.0f ? v : NEG_SLOPE * v;
    float t = v * a[lane];
    #pragma unroll
    for (int off = 32; off; off >>= 1) t += __shfl_xor(t, off);
    if (lane == 0) {
        e[wid] = t;
        atomicMax(&m[d], enc_f32(t));
    }
}

// ex = exp(e - m[d]); denom[d] += ex  (e overwritten in place with ex)
__global__ void k_exp(const int* __restrict__ dst, const unsigned* __restrict__ m,
                      float* __restrict__ e, float* __restrict__ denom, int E, int N) {
    int i = blockIdx.x * blockDim.x + threadIdx.x;
    int ET = E + N;
    if (i >= ET) return;
    int d = (i < E) ? dst[i] : (i - E);
    float ex = __expf(e[i] - dec_f32(m[d]));
    e[i] = ex;
    atomicAdd(&denom[d], ex);
}

// out[d] += (ex/denom[d]) * xl[s]; one wave per edge
__global__ void k_agg(const int* __restrict__ src, const int* __restrict__ dst,
                      const float* __restrict__ A, const float* __restrict__ e,
                      const float* __restrict__ denom, float* __restrict__ out, int E, int N) {
    int wid = (int)((blockIdx.x * (size_t)blockDim.x + threadIdx.x) >> 6);
    int lane = threadIdx.x & 63;
    int ET = E + N;
    if (wid >= ET) return;
    int s, d;
    if (wid < E) { s = src[wid]; d = dst[wid]; } else { s = d = wid - E; }
    float alpha = e[wid] / denom[d];
    atomicAdd(&out[(size_t)d * HID + lane], alpha * A[(size_t)s * HID + lane]);
}

// h2 = tanh(out + b1), in place
__global__ void k_bias_tanh(float* __restrict__ C, const float* __restrict__ b, int N) {
    int idx = blockIdx.x * blockDim.x + threadIdx.x;
    if (idx >= N * HID) return;
    C[idx] = tanhf(C[idx] + b[idx & 63]);
}

// layer-2 transforms: xl2 = h2@Wl2+bl2, xr2 = h2@Wr2+br2 (64x64 each)
__global__ void k_xfrm2(const float* __restrict__ H,
                        const float* __restrict__ Wl, const float* __restrict__ bl,
                        const float* __restrict__ Wr, const float* __restrict__ br,
                        float* __restrict__ A, float* __restrict__ B, int N) {
    int idx = blockIdx.x * blockDim.x + threadIdx.x;
    if (idx >= N * HID) return;
    int n = idx >> 6, c = idx & 63;
    const float* h = H + (size_t)n * HID;
    float sl = bl[c], sr = br[c];
    #pragma unroll 8
    for (int k = 0; k < HID; ++k) {
        float hv = h[k];
        sl += hv * Wl[k * HID + c];
        sr += hv * Wr[k * HID + c];
    }
    A[idx] = sl;
    B[idx] = sr;
}

__global__ void k_init_g(unsigned* __restrict__ g, int GH) {
    int i = blockIdx.x * blockDim.x + threadIdx.x;
    if (i < GH) g[i] = 0x007FFFFFu;  // enc(-inf)
}

// global max pool (with +b2 folded in): g[batch[n]][c] = max over nodes
__global__ void k_pool(const float* __restrict__ C, const float* __restrict__ b2,
                       const int* __restrict__ batch, unsigned* __restrict__ g, int N) {
    int idx = blockIdx.x * blockDim.x + threadIdx.x;
    if (idx >= N * HID) return;
    int n = idx >> 6, c = idx & 63;
    float v = C[idx] + b2[c];
    atomicMax(&g[(size_t)batch[n] * HID + c], enc_f32(v));
}

// out = g @ W3 + b3  [G,2]
__global__ void k_final(const unsigned* __restrict__ g, const float* __restrict__ W3,
                        const float* __restrict__ b3, float* __restrict__ out, int G) {
    int idx = blockIdx.x * blockDim.x + threadIdx.x;
    if (idx >= G * 2) return;
    int gi = idx >> 1, j = idx & 1;
    float sum = b3[j];
    #pragma unroll 8
    for (int k = 0; k < HID; ++k) sum += dec_f32(g[(size_t)gi * HID + k]) * W3[k * 2 + j];
    out[idx] = sum;
}

extern "C" void kernel_launch(void* const* d_in, const int* in_sizes, int n_in,
                              void* d_out, int out_size, void* d_ws, size_t ws_size,
                              hipStream_t stream) {
    const float* x     = (const float*)d_in[0];
    const int*   ei    = (const int*)d_in[1];
    const int*   batch = (const int*)d_in[2];
    const float* Wl1 = (const float*)d_in[3];
    const float* bl1 = (const float*)d_in[4];
    const float* Wr1 = (const float*)d_in[5];
    const float* br1 = (const float*)d_in[6];
    const float* a1  = (const float*)d_in[7];
    const float* b1  = (const float*)d_in[8];
    const float* Wl2 = (const float*)d_in[9];
    const float* bl2 = (const float*)d_in[10];
    const float* Wr2 = (const float*)d_in[11];
    const float* br2 = (const float*)d_in[12];
    const float* a2  = (const float*)d_in[13];
    const float* b2  = (const float*)d_in[14];
    const float* W3  = (const float*)d_in[15];
    const float* b3  = (const float*)d_in[16];

    const int N = in_sizes[0];          // 100000
    const int E = in_sizes[1] / 2;      // 1600000
    const int G = out_size / 2;         // 1000
    const int ET = E + N;

    // workspace layout (floats): [A][B][C][m][denom][deg_in][deg_out][e][g]
    float* ws = (float*)d_ws;
    size_t off = 0;
    float*    A       = ws + off; off += (size_t)N * HID;
    float*    Bv      = ws + off; off += (size_t)N * HID;
    float*    C       = ws + off; off += (size_t)N * HID;
    unsigned* m       = (unsigned*)(ws + off); off += N;
    float*    denom   = ws + off; off += N;
    float*    deg_in  = ws + off; off += N;
    float*    deg_out = ws + off; off += N;
    float*    e       = ws + off; off += ET;
    unsigned* g       = (unsigned*)(ws + off); off += (size_t)G * HID;

    const int* src  = ei;
    const int* dstp = ei + E;

    const int BT = 256;
    dim3 blk(BT);
    int grid_edge  = (E + BT - 1) / BT;
    int grid_nodeC = (N * HID + BT - 1) / BT;
    int grid_wave  = (int)(((size_t)ET * 64 + BT - 1) / BT);
    int grid_et    = (ET + BT - 1) / BT;

    // zero [C][m][denom][deg_in][deg_out] in one shot (contiguous)
    hipMemsetAsync(C, 0, ((size_t)N * HID + 4 * (size_t)N) * sizeof(float), stream);

    // ---- layer 1 ----
    k_deg<<<grid_edge, blk, 0, stream>>>(src, dstp, deg_in, deg_out, E);
    k_xfrm1<<<grid_nodeC, blk, 0, stream>>>(x, deg_in, deg_out, Wl1, bl1, Wr1, br1, A, Bv, N);
    k_logit<<<grid_wave, blk, 0, stream>>>(src, dstp, A, Bv, a1, e, m, E, N);
    k_exp<<<grid_et, blk, 0, stream>>>(dstp, m, e, denom, E, N);
    k_agg<<<grid_wave, blk, 0, stream>>>(src, dstp, A, e, denom, C, E, N);
    k_bias_tanh<<<grid_nodeC, blk, 0, stream>>>(C, b1, N);

    // ---- layer 2 ----
    k_xfrm2<<<grid_nodeC, blk, 0, stream>>>(C, Wl2, bl2, Wr2, br2, A, Bv, N);
    // zero [C][m][denom] (contiguous)
    hipMemsetAsync(C, 0, ((size_t)N * HID + 2 * (size_t)N) * sizeof(float), stream);
    k_logit<<<grid_wave, blk, 0, stream>>>(src, dstp, A, Bv, a2, e, m, E, N);
    k_exp<<<grid_et, blk, 0, stream>>>(dstp, m, e, denom, E, N);
    k_agg<<<grid_wave, blk, 0, stream>>>(src, dstp, A, e, denom, C, E, N);

    // ---- pool + final linear ----
    k_init_g<<<(G * HID + BT - 1) / BT, blk, 0, stream>>>(g, G * HID);
    k_pool<<<grid_nodeC, blk, 0, stream>>>(C, b2, batch, g, N);
    k_final<<<(G * 2 + BT - 1) / BT, blk, 0, stream>>>(g, W3, b3, (float*)d_out, G);
}

// Round 2
// 885.015 us; speedup vs baseline: 2.1470x; 2.1470x over previous
//
#include <hip/hip_runtime.h>
#include <hip/hip_bf16.h>

#define HID 64
#define NEG_SLOPE 0.2f
#define SCAN_T 1024

// ---- order-preserving float <-> uint encoding for atomicMax on floats ----
__device__ __forceinline__ unsigned enc_f32(float f) {
    unsigned u = __float_as_uint(f);
    return (u & 0x80000000u) ? ~u : (u | 0x80000000u);
}
__device__ __forceinline__ float dec_f32(unsigned u) {
    unsigned b = (u & 0x80000000u) ? (u & 0x7FFFFFFFu) : ~u;
    return __uint_as_float(b);
}

// degree counts via atomics (float, used directly as layer-1 features)
__global__ void k_deg(const int* __restrict__ src, const int* __restrict__ dst,
                      float* deg_in, float* deg_out, int E) {
    int i = blockIdx.x * blockDim.x + threadIdx.x;
    if (i < E) {
        atomicAdd(&deg_out[src[i]], 1.0f);
        atomicAdd(&deg_in[dst[i]], 1.0f);
    }
}

// layer-1 transforms: h = [x, deg_in, deg_out] (N,3); A = h@Wl+bl, B = h@Wr+br
__global__ void k_xfrm1(const float* __restrict__ x, const float* __restrict__ deg_in,
                        const float* __restrict__ deg_out,
                        const float* __restrict__ Wl, const float* __restrict__ bl,
                        const float* __restrict__ Wr, const float* __restrict__ br,
                        float* __restrict__ A, float* __restrict__ B, int N) {
    int idx = blockIdx.x * blockDim.x + threadIdx.x;
    if (idx >= N * HID) return;
    int n = idx >> 6, c = idx & 63;
    float h0 = x[n], h1 = deg_in[n], h2 = deg_out[n];
    A[idx] = h0 * Wl[c] + h1 * Wl[HID + c] + h2 * Wl[2 * HID + c] + bl[c];
    B[idx] = h0 * Wr[c] + h1 * Wr[HID + c] + h2 * Wr[2 * HID + c] + br[c];
}

// single-block exclusive scan of int(deg_in) -> row_off[0..N], row_off[N]=E
__global__ void k_scan(const float* __restrict__ deg_in, int* __restrict__ row_off, int N) {
    __shared__ int sums[SCAN_T];
    int t = threadIdx.x;
    int chunk = (N + SCAN_T - 1) / SCAN_T;
    int lo = t * chunk;
    int hi = lo + chunk; if (hi > N) hi = N;
    int s = 0;
    for (int i = lo; i < hi; ++i) s += (int)deg_in[i];
    sums[t] = s;
    __syncthreads();
    for (int off = 1; off < SCAN_T; off <<= 1) {
        int u = (t >= off) ? sums[t - off] : 0;
        __syncthreads();
        sums[t] += u;
        __syncthreads();
    }
    int run = sums[t] - s;  // exclusive prefix of this chunk
    for (int i = lo; i < hi; ++i) {
        row_off[i] = run;
        run += (int)deg_in[i];
    }
    if (t == 0) row_off[N] = sums[SCAN_T - 1];
}

__global__ void k_copy_int(const int* __restrict__ a, int* __restrict__ b, int n) {
    int i = blockIdx.x * blockDim.x + threadIdx.x;
    if (i < n) b[i] = a[i];
}

// scatter edges into CSR-by-dst (order within a row is nondeterministic; fp-sum tolerant)
__global__ void k_scatter(const int* __restrict__ src, const int* __restrict__ dst,
                          int* __restrict__ cursor, int* __restrict__ csr_src, int E) {
    int i = blockIdx.x * blockDim.x + threadIdx.x;
    if (i >= E) return;
    int pos = atomicAdd(&cursor[dst[i]], 1);
    csr_src[pos] = src[i];
}

// Fused GATv2 layer: one wave per dst node, online softmax, no atomics.
// out[d] = segsum(alpha * A[s]) + bias   (tanh applied if TANH)
template <bool TANH>
__global__ void k_gat_fused(const int* __restrict__ csr_src, const int* __restrict__ row_off,
                            const float* __restrict__ A, const float* __restrict__ B,
                            const float* __restrict__ aw, const float* __restrict__ bias,
                            float* __restrict__ out, int N) {
    int wid = (int)((blockIdx.x * (size_t)blockDim.x + threadIdx.x) >> 6);
    int lane = threadIdx.x & 63;
    if (wid >= N) return;
    int d = wid;
    float a_l = aw[lane];
    float xr = B[(size_t)d * HID + lane];

    // self loop seeds the online-softmax state
    float ar = A[(size_t)d * HID + lane];
    float v = ar + xr; v = v > 0.0f ? v : NEG_SLOPE * v;
    float t = v * a_l;
    #pragma unroll
    for (int o = 32; o; o >>= 1) t += __shfl_xor(t, o);
    float m = t;
    float denom = 1.0f;
    float acc = ar;

    int lo = row_off[d], hi = row_off[d + 1];
    int k = lo;
    for (; k + 1 < hi; k += 2) {
        int s0 = csr_src[k], s1 = csr_src[k + 1];
        float ar0 = A[(size_t)s0 * HID + lane];
        float ar1 = A[(size_t)s1 * HID + lane];
        float v0 = ar0 + xr; v0 = v0 > 0.0f ? v0 : NEG_SLOPE * v0;
        float v1 = ar1 + xr; v1 = v1 > 0.0f ? v1 : NEG_SLOPE * v1;
        float t0 = v0 * a_l, t1 = v1 * a_l;
        #pragma unroll
        for (int o = 32; o; o >>= 1) { t0 += __shfl_xor(t0, o); t1 += __shfl_xor(t1, o); }
        if (t0 > m) { float sc = __expf(m - t0); acc *= sc; denom *= sc; m = t0; }
        float w0 = __expf(t0 - m);
        denom += w0; acc = fmaf(w0, ar0, acc);
        if (t1 > m) { float sc = __expf(m - t1); acc *= sc; denom *= sc; m = t1; }
        float w1 = __expf(t1 - m);
        denom += w1; acc = fmaf(w1, ar1, acc);
    }
    if (k < hi) {
        int s0 = csr_src[k];
        float ar0 = A[(size_t)s0 * HID + lane];
        float v0 = ar0 + xr; v0 = v0 > 0.0f ? v0 : NEG_SLOPE * v0;
        float t0 = v0 * a_l;
        #pragma unroll
        for (int o = 32; o; o >>= 1) t0 += __shfl_xor(t0, o);
        if (t0 > m) { float sc = __expf(m - t0); acc *= sc; denom *= sc; m = t0; }
        float w0 = __expf(t0 - m);
        denom += w0; acc = fmaf(w0, ar0, acc);
    }

    float o = acc / denom + bias[lane];
    if (TANH) o = tanhf(o);
    out[(size_t)d * HID + lane] = o;
}

// layer-2 transforms: A = H@Wl2+bl2, B = H@Wr2+br2 (64x64 each)
__global__ void k_xfrm2(const float* __restrict__ H,
                        const float* __restrict__ Wl, const float* __restrict__ bl,
                        const float* __restrict__ Wr, const float* __restrict__ br,
                        float* __restrict__ A, float* __restrict__ B, int N) {
    int idx = blockIdx.x * blockDim.x + threadIdx.x;
    if (idx >= N * HID) return;
    int n = idx >> 6, c = idx & 63;
    const float* h = H + (size_t)n * HID;
    float sl = bl[c], sr = br[c];
    #pragma unroll 8
    for (int kk = 0; kk < HID; ++kk) {
        float hv = h[kk];
        sl += hv * Wl[kk * HID + c];
        sr += hv * Wr[kk * HID + c];
    }
    A[idx] = sl;
    B[idx] = sr;
}

__global__ void k_init_g(unsigned* __restrict__ g, int GH) {
    int i = blockIdx.x * blockDim.x + threadIdx.x;
    if (i < GH) g[i] = 0x007FFFFFu;  // enc(-inf)
}

// global max pool (bias already folded into C)
__global__ void k_pool(const float* __restrict__ C, const int* __restrict__ batch,
                       unsigned* __restrict__ g, int N) {
    int idx = blockIdx.x * blockDim.x + threadIdx.x;
    if (idx >= N * HID) return;
    int n = idx >> 6, c = idx & 63;
    atomicMax(&g[(size_t)batch[n] * HID + c], enc_f32(C[idx]));
}

// out = g @ W3 + b3  [G,2]
__global__ void k_final(const unsigned* __restrict__ g, const float* __restrict__ W3,
                        const float* __restrict__ b3, float* __restrict__ out, int G) {
    int idx = blockIdx.x * blockDim.x + threadIdx.x;
    if (idx >= G * 2) return;
    int gi = idx >> 1, j = idx & 1;
    float sum = b3[j];
    #pragma unroll 8
    for (int kk = 0; kk < HID; ++kk) sum += dec_f32(g[(size_t)gi * HID + kk]) * W3[kk * 2 + j];
    out[idx] = sum;
}

extern "C" void kernel_launch(void* const* d_in, const int* in_sizes, int n_in,
                              void* d_out, int out_size, void* d_ws, size_t ws_size,
                              hipStream_t stream) {
    const float* x     = (const float*)d_in[0];
    const int*   ei    = (const int*)d_in[1];
    const int*   batch = (const int*)d_in[2];
    const float* Wl1 = (const float*)d_in[3];
    const float* bl1 = (const float*)d_in[4];
    const float* Wr1 = (const float*)d_in[5];
    const float* br1 = (const float*)d_in[6];
    const float* a1  = (const float*)d_in[7];
    const float* b1  = (const float*)d_in[8];
    const float* Wl2 = (const float*)d_in[9];
    const float* bl2 = (const float*)d_in[10];
    const float* Wr2 = (const float*)d_in[11];
    const float* br2 = (const float*)d_in[12];
    const float* a2  = (const float*)d_in[13];
    const float* b2  = (const float*)d_in[14];
    const float* W3  = (const float*)d_in[15];
    const float* b3  = (const float*)d_in[16];

    const int N = in_sizes[0];          // 100000
    const int E = in_sizes[1] / 2;      // 1600000
    const int G = out_size / 2;         // 1000

    // workspace layout
    float* ws = (float*)d_ws;
    size_t off = 0;
    float*    A       = ws + off; off += (size_t)N * HID;
    float*    Bv      = ws + off; off += (size_t)N * HID;
    float*    C       = ws + off; off += (size_t)N * HID;
    float*    deg_in  = ws + off; off += N;
    float*    deg_out = ws + off; off += N;
    int*      row_off = (int*)(ws + off); off += N + 1;
    int*      cursor  = (int*)(ws + off); off += N;
    int*      csr_src = (int*)(ws + off); off += E;
    unsigned* g       = (unsigned*)(ws + off); off += (size_t)G * HID;

    const int* src  = ei;
    const int* dstp = ei + E;

    const int BT = 256;
    dim3 blk(BT);
    int grid_edge  = (E + BT - 1) / BT;
    int grid_nodeC = (N * HID + BT - 1) / BT;
    int grid_wavN  = (int)(((size_t)N * 64 + BT - 1) / BT);

    // zero degree buffers (contiguous)
    hipMemsetAsync(deg_in, 0, 2 * (size_t)N * sizeof(float), stream);

    // ---- CSR build + layer-1 transforms ----
    k_deg<<<grid_edge, blk, 0, stream>>>(src, dstp, deg_in, deg_out, E);
    k_xfrm1<<<grid_nodeC, blk, 0, stream>>>(x, deg_in, deg_out, Wl1, bl1, Wr1, br1, A, Bv, N);
    k_scan<<<1, SCAN_T, 0, stream>>>(deg_in, row_off, N);
    k_copy_int<<<(N + BT - 1) / BT, blk, 0, stream>>>(row_off, cursor, N);
    k_scatter<<<grid_edge, blk, 0, stream>>>(src, dstp, cursor, csr_src, E);

    // ---- layer 1 (fused logit+softmax+aggregate, +b1, tanh) ----
    k_gat_fused<true><<<grid_wavN, blk, 0, stream>>>(csr_src, row_off, A, Bv, a1, b1, C, N);

    // ---- layer 2 ----
    k_xfrm2<<<grid_nodeC, blk, 0, stream>>>(C, Wl2, bl2, Wr2, br2, A, Bv, N);
    k_gat_fused<false><<<grid_wavN, blk, 0, stream>>>(csr_src, row_off, A, Bv, a2, b2, C, N);

    // ---- pool + final linear ----
    k_init_g<<<(G * HID + BT - 1) / BT, blk, 0, stream>>>(g, G * HID);
    k_pool<<<grid_nodeC, blk, 0, stream>>>(C, batch, g, N);
    k_final<<<(G * 2 + BT - 1) / BT, blk, 0, stream>>>(g, W3, b3, (float*)d_out, G);
}

// Round 3
// 738.159 us; speedup vs baseline: 2.5742x; 1.1989x over previous
//
#include <hip/hip_runtime.h>
#include <hip/hip_bf16.h>

#define HID 64
#define NEG_SLOPE 0.2f

// ---- order-preserving float <-> uint encoding for atomicMax on floats ----
__device__ __forceinline__ unsigned enc_f32(float f) {
    unsigned u = __float_as_uint(f);
    return (u & 0x80000000u) ? ~u : (u | 0x80000000u);
}
__device__ __forceinline__ float dec_f32(unsigned u) {
    unsigned b = (u & 0x80000000u) ? (u & 0x7FFFFFFFu) : ~u;
    return __uint_as_float(b);
}

// degree counts via atomics (float, used directly as layer-1 features)
__global__ void k_deg(const int* __restrict__ src, const int* __restrict__ dst,
                      float* deg_in, float* deg_out, int E) {
    int i = blockIdx.x * blockDim.x + threadIdx.x;
    if (i < E) {
        atomicAdd(&deg_out[src[i]], 1.0f);
        atomicAdd(&deg_in[dst[i]], 1.0f);
    }
}

// layer-1 transforms: h = [x, deg_in, deg_out] (N,3); A = h@Wl+bl, B = h@Wr+br
__global__ void k_xfrm1(const float* __restrict__ x, const float* __restrict__ deg_in,
                        const float* __restrict__ deg_out,
                        const float* __restrict__ Wl, const float* __restrict__ bl,
                        const float* __restrict__ Wr, const float* __restrict__ br,
                        float* __restrict__ A, float* __restrict__ B, int N) {
    int idx = blockIdx.x * blockDim.x + threadIdx.x;
    if (idx >= N * HID) return;
    int n = idx >> 6, c = idx & 63;
    float h0 = x[n], h1 = deg_in[n], h2 = deg_out[n];
    A[idx] = h0 * Wl[c] + h1 * Wl[HID + c] + h2 * Wl[2 * HID + c] + bl[c];
    B[idx] = h0 * Wr[c] + h1 * Wr[HID + c] + h2 * Wr[2 * HID + c] + br[c];
}

// ---- hierarchical exclusive scan of int(deg_in): 3 stages ----
// stage 1: per-block (256 elems) exclusive scan + block total
__global__ void k_scan_block(const float* __restrict__ deg_in, int* __restrict__ row_off,
                             int* __restrict__ partials, int N) {
    __shared__ int s[256];
    int t = threadIdx.x;
    int i = blockIdx.x * 256 + t;
    int v = (i < N) ? (int)deg_in[i] : 0;
    s[t] = v;
    __syncthreads();
    for (int off = 1; off < 256; off <<= 1) {
        int u = (t >= off) ? s[t - off] : 0;
        __syncthreads();
        s[t] += u;
        __syncthreads();
    }
    if (i < N) row_off[i] = s[t] - v;  // exclusive within block
    if (t == 255) partials[blockIdx.x] = s[255];
}

// stage 2: single-block exclusive scan of block partials (nb <= 1024)
__global__ void k_scan_partials(int* __restrict__ partials, int nb) {
    __shared__ int s[1024];
    int t = threadIdx.x;
    int v = (t < nb) ? partials[t] : 0;
    s[t] = v;
    __syncthreads();
    for (int off = 1; off < 1024; off <<= 1) {
        int u = (t >= off) ? s[t - off] : 0;
        __syncthreads();
        s[t] += u;
        __syncthreads();
    }
    if (t < nb) partials[t] = s[t] - v;  // exclusive
}

// stage 3: add block offsets; also initialize cursor and row_off[N]
__global__ void k_scan_add(int* __restrict__ row_off, int* __restrict__ cursor,
                           const int* __restrict__ partials, int N, int E) {
    int i = blockIdx.x * 256 + threadIdx.x;
    if (i < N) {
        int r = row_off[i] + partials[i >> 8];
        row_off[i] = r;
        cursor[i] = r;
    }
    if (i == 0) row_off[N] = E;
}

// scatter edges into CSR-by-dst (order within a row is nondeterministic; fp-sum tolerant)
__global__ void k_scatter(const int* __restrict__ src, const int* __restrict__ dst,
                          int* __restrict__ cursor, int* __restrict__ csr_src, int E) {
    int i = blockIdx.x * blockDim.x + threadIdx.x;
    if (i >= E) return;
    int pos = atomicAdd(&cursor[dst[i]], 1);
    csr_src[pos] = src[i];
}

// Fused GATv2 layer: one wave per dst node, online softmax, no atomics.
// out[d] = segsum(alpha * A[s]) + bias   (tanh applied if TANH)
template <bool TANH>
__global__ void k_gat_fused(const int* __restrict__ csr_src, const int* __restrict__ row_off,
                            const float* __restrict__ A, const float* __restrict__ B,
                            const float* __restrict__ aw, const float* __restrict__ bias,
                            float* __restrict__ out, int N) {
    int wid = (int)((blockIdx.x * (size_t)blockDim.x + threadIdx.x) >> 6);
    int lane = threadIdx.x & 63;
    if (wid >= N) return;
    int d = wid;
    float a_l = aw[lane];
    float xr = B[(size_t)d * HID + lane];

    // self loop seeds the online-softmax state
    float ar = A[(size_t)d * HID + lane];
    float v = ar + xr; v = v > 0.0f ? v : NEG_SLOPE * v;
    float t = v * a_l;
    #pragma unroll
    for (int o = 32; o; o >>= 1) t += __shfl_xor(t, o);
    float m = t;
    float denom = 1.0f;
    float acc = ar;

    int lo = row_off[d], hi = row_off[d + 1];
    int k = lo;
    for (; k + 1 < hi; k += 2) {
        int s0 = csr_src[k], s1 = csr_src[k + 1];
        float ar0 = A[(size_t)s0 * HID + lane];
        float ar1 = A[(size_t)s1 * HID + lane];
        float v0 = ar0 + xr; v0 = v0 > 0.0f ? v0 : NEG_SLOPE * v0;
        float v1 = ar1 + xr; v1 = v1 > 0.0f ? v1 : NEG_SLOPE * v1;
        float t0 = v0 * a_l, t1 = v1 * a_l;
        #pragma unroll
        for (int o = 32; o; o >>= 1) { t0 += __shfl_xor(t0, o); t1 += __shfl_xor(t1, o); }
        if (t0 > m) { float sc = __expf(m - t0); acc *= sc; denom *= sc; m = t0; }
        float w0 = __expf(t0 - m);
        denom += w0; acc = fmaf(w0, ar0, acc);
        if (t1 > m) { float sc = __expf(m - t1); acc *= sc; denom *= sc; m = t1; }
        float w1 = __expf(t1 - m);
        denom += w1; acc = fmaf(w1, ar1, acc);
    }
    if (k < hi) {
        int s0 = csr_src[k];
        float ar0 = A[(size_t)s0 * HID + lane];
        float v0 = ar0 + xr; v0 = v0 > 0.0f ? v0 : NEG_SLOPE * v0;
        float t0 = v0 * a_l;
        #pragma unroll
        for (int o = 32; o; o >>= 1) t0 += __shfl_xor(t0, o);
        if (t0 > m) { float sc = __expf(m - t0); acc *= sc; denom *= sc; m = t0; }
        float w0 = __expf(t0 - m);
        denom += w0; acc = fmaf(w0, ar0, acc);
    }

    float o = acc / denom + bias[lane];
    if (TANH) o = tanhf(o);
    out[(size_t)d * HID + lane] = o;
}

// layer-2 transforms: A = H@Wl2+bl2, B = H@Wr2+br2 (64x64 each)
__global__ void k_xfrm2(const float* __restrict__ H,
                        const float* __restrict__ Wl, const float* __restrict__ bl,
                        const float* __restrict__ Wr, const float* __restrict__ br,
                        float* __restrict__ A, float* __restrict__ B, int N) {
    int idx = blockIdx.x * blockDim.x + threadIdx.x;
    if (idx >= N * HID) return;
    int n = idx >> 6, c = idx & 63;
    const float* h = H + (size_t)n * HID;
    float sl = bl[c], sr = br[c];
    #pragma unroll 8
    for (int kk = 0; kk < HID; ++kk) {
        float hv = h[kk];
        sl += hv * Wl[kk * HID + c];
        sr += hv * Wr[kk * HID + c];
    }
    A[idx] = sl;
    B[idx] = sr;
}

__global__ void k_init_g(unsigned* __restrict__ g, int GH) {
    int i = blockIdx.x * blockDim.x + threadIdx.x;
    if (i < GH) g[i] = 0x007FFFFFu;  // enc(-inf)
}

// global max pool (bias already folded into C)
__global__ void k_pool(const float* __restrict__ C, const int* __restrict__ batch,
                       unsigned* __restrict__ g, int N) {
    int idx = blockIdx.x * blockDim.x + threadIdx.x;
    if (idx >= N * HID) return;
    int n = idx >> 6, c = idx & 63;
    atomicMax(&g[(size_t)batch[n] * HID + c], enc_f32(C[idx]));
}

// out = g @ W3 + b3  [G,2]
__global__ void k_final(const unsigned* __restrict__ g, const float* __restrict__ W3,
                        const float* __restrict__ b3, float* __restrict__ out, int G) {
    int idx = blockIdx.x * blockDim.x + threadIdx.x;
    if (idx >= G * 2) return;
    int gi = idx >> 1, j = idx & 1;
    float sum = b3[j];
    #pragma unroll 8
    for (int kk = 0; kk < HID; ++kk) sum += dec_f32(g[(size_t)gi * HID + kk]) * W3[kk * 2 + j];
    out[idx] = sum;
}

extern "C" void kernel_launch(void* const* d_in, const int* in_sizes, int n_in,
                              void* d_out, int out_size, void* d_ws, size_t ws_size,
                              hipStream_t stream) {
    const float* x     = (const float*)d_in[0];
    const int*   ei    = (const int*)d_in[1];
    const int*   batch = (const int*)d_in[2];
    const float* Wl1 = (const float*)d_in[3];
    const float* bl1 = (const float*)d_in[4];
    const float* Wr1 = (const float*)d_in[5];
    const float* br1 = (const float*)d_in[6];
    const float* a1  = (const float*)d_in[7];
    const float* b1  = (const float*)d_in[8];
    const float* Wl2 = (const float*)d_in[9];
    const float* bl2 = (const float*)d_in[10];
    const float* Wr2 = (const float*)d_in[11];
    const float* br2 = (const float*)d_in[12];
    const float* a2  = (const float*)d_in[13];
    const float* b2  = (const float*)d_in[14];
    const float* W3  = (const float*)d_in[15];
    const float* b3  = (const float*)d_in[16];

    const int N = in_sizes[0];          // 100000
    const int E = in_sizes[1] / 2;      // 1600000
    const int G = out_size / 2;         // 1000

    // workspace layout
    float* ws = (float*)d_ws;
    size_t off = 0;
    float*    A       = ws + off; off += (size_t)N * HID;
    float*    Bv      = ws + off; off += (size_t)N * HID;
    float*    C       = ws + off; off += (size_t)N * HID;
    float*    deg_in  = ws + off; off += N;
    float*    deg_out = ws + off; off += N;
    int*      row_off = (int*)(ws + off); off += N + 1;
    int*      cursor  = (int*)(ws + off); off += N;
    int*      csr_src = (int*)(ws + off); off += E;
    int*      partials= (int*)(ws + off); off += 1024;
    unsigned* g       = (unsigned*)(ws + off); off += (size_t)G * HID;

    const int* src  = ei;
    const int* dstp = ei + E;

    const int BT = 256;
    dim3 blk(BT);
    int grid_edge  = (E + BT - 1) / BT;
    int grid_nodeC = (N * HID + BT - 1) / BT;
    int grid_wavN  = (int)(((size_t)N * 64 + BT - 1) / BT);
    int nb_scan    = (N + 255) / 256;

    // zero degree buffers (contiguous)
    hipMemsetAsync(deg_in, 0, 2 * (size_t)N * sizeof(float), stream);

    // ---- CSR build + layer-1 transforms ----
    k_deg<<<grid_edge, blk, 0, stream>>>(src, dstp, deg_in, deg_out, E);
    k_xfrm1<<<grid_nodeC, blk, 0, stream>>>(x, deg_in, deg_out, Wl1, bl1, Wr1, br1, A, Bv, N);
    k_scan_block<<<nb_scan, 256, 0, stream>>>(deg_in, row_off, partials, N);
    k_scan_partials<<<1, 1024, 0, stream>>>(partials, nb_scan);
    k_scan_add<<<nb_scan, 256, 0, stream>>>(row_off, cursor, partials, N, E);
    k_scatter<<<grid_edge, blk, 0, stream>>>(src, dstp, cursor, csr_src, E);

    // ---- layer 1 (fused logit+softmax+aggregate, +b1, tanh) ----
    k_gat_fused<true><<<grid_wavN, blk, 0, stream>>>(csr_src, row_off, A, Bv, a1, b1, C, N);

    // ---- layer 2 ----
    k_xfrm2<<<grid_nodeC, blk, 0, stream>>>(C, Wl2, bl2, Wr2, br2, A, Bv, N);
    k_gat_fused<false><<<grid_wavN, blk, 0, stream>>>(csr_src, row_off, A, Bv, a2, b2, C, N);

    // ---- pool + final linear ----
    k_init_g<<<(G * HID + BT - 1) / BT, blk, 0, stream>>>(g, G * HID);
    k_pool<<<grid_nodeC, blk, 0, stream>>>(C, batch, g, N);
    k_final<<<(G * 2 + BT - 1) / BT, blk, 0, stream>>>(g, W3, b3, (float*)d_out, G);
}

// Round 4
// 508.301 us; speedup vs baseline: 3.7382x; 1.4522x over previous
//
#include <hip/hip_runtime.h>
#include <hip/hip_bf16.h>

#define HID 64
#define NEG_SLOPE 0.2f
#define BLK_E 8192        // edges per block in binning passes
#define EDGE_CAP 6144     // LDS edge cache per bin (bin mean ~4096, +32 sigma)

// ============ counting-sort CSR build (no global atomics) ============

// pass A: per-block LDS histograms of src>>8 and dst>>8
__global__ void k_hist2(const int* __restrict__ src, const int* __restrict__ dst,
                        int* __restrict__ histS, int* __restrict__ histD,
                        int E, int NB, int NBLK) {
    __shared__ int hs[512], hd[512];
    int t = threadIdx.x, blk = blockIdx.x;
    for (int b = t; b < NB; b += 1024) { hs[b] = 0; hd[b] = 0; }
    __syncthreads();
    int base = blk * BLK_E;
    #pragma unroll
    for (int k = 0; k < BLK_E / 1024; ++k) {
        int i = base + k * 1024 + t;
        if (i < E) {
            atomicAdd(&hs[src[i] >> 8], 1);
            atomicAdd(&hd[dst[i] >> 8], 1);
        }
    }
    __syncthreads();
    for (int b = t; b < NB; b += 1024) {
        histS[b * NBLK + blk] = hs[b];
        histD[b * NBLK + blk] = hd[b];
    }
}

// pass B: per-bin scan over blocks -> exclusive per-(bin,block) base + bin totals
__global__ void k_binscan(int* __restrict__ histS, int* __restrict__ histD,
                          int* __restrict__ totS, int* __restrict__ totD,
                          int NB, int NBLK) {
    __shared__ int s[256];
    int b = blockIdx.x;
    int* hist = histS; int* tot = totS;
    if (b >= NB) { b -= NB; hist = histD; tot = totD; }
    int t = threadIdx.x;
    int v = (t < NBLK) ? hist[b * NBLK + t] : 0;
    s[t] = v;
    __syncthreads();
    for (int o = 1; o < 256; o <<= 1) {
        int u = (t >= o) ? s[t - o] : 0;
        __syncthreads();
        s[t] += u;
        __syncthreads();
    }
    if (t < NBLK) hist[b * NBLK + t] = s[t] - v;  // exclusive within bin
    if (t == 255) tot[b] = s[255];
}

// pass C: scan bin totals -> bin start offsets (both sides); also row_off[N]=E
__global__ void k_binoffset(const int* __restrict__ totS, const int* __restrict__ totD,
                            int* __restrict__ bsS, int* __restrict__ bsD,
                            int NB, int E, int* __restrict__ row_off, int N) {
    __shared__ int s[512];
    int t = threadIdx.x;
    int v = (t < NB) ? totS[t] : 0;
    s[t] = v; __syncthreads();
    for (int o = 1; o < 512; o <<= 1) {
        int u = (t >= o) ? s[t - o] : 0;
        __syncthreads(); s[t] += u; __syncthreads();
    }
    if (t < NB) bsS[t] = s[t] - v;
    if (t == 0) bsS[NB] = E;
    __syncthreads();
    v = (t < NB) ? totD[t] : 0;
    s[t] = v; __syncthreads();
    for (int o = 1; o < 512; o <<= 1) {
        int u = (t >= o) ? s[t - o] : 0;
        __syncthreads(); s[t] += u; __syncthreads();
    }
    if (t < NB) bsD[t] = s[t] - v;
    if (t == 0) { bsD[NB] = E; row_off[N] = E; }
}

// pass D: scatter edges into bin segments (LDS allocation cursors, no global atomics)
__global__ void k_scatter_bins(const int* __restrict__ src, const int* __restrict__ dst,
                               const int* __restrict__ histS, const int* __restrict__ histD,
                               const int* __restrict__ bsS, const int* __restrict__ bsD,
                               unsigned* __restrict__ packS, unsigned* __restrict__ packD,
                               int E, int NB, int NBLK) {
    __shared__ int baseS[512], baseD[512];
    int t = threadIdx.x, blk = blockIdx.x;
    for (int b = t; b < NB; b += 1024) {
        baseS[b] = bsS[b] + histS[b * NBLK + blk];
        baseD[b] = bsD[b] + histD[b * NBLK + blk];
    }
    __syncthreads();
    int base = blk * BLK_E;
    #pragma unroll
    for (int k = 0; k < BLK_E / 1024; ++k) {
        int i = base + k * 1024 + t;
        if (i < E) {
            int sv = src[i], dv = dst[i];
            int pD = atomicAdd(&baseD[dv >> 8], 1);
            packD[pD] = ((unsigned)(dv & 255) << 24) | (unsigned)sv;  // src < 2^24
            int pS = atomicAdd(&baseS[sv >> 8], 1);
            packS[pS] = (unsigned)(sv & 255);
        }
    }
}

// pass E (dst side): per-bin exact counts + scan -> deg_in, row_off, sorted csr_src
__global__ void k_csr_bin(const unsigned* __restrict__ packD, const int* __restrict__ bsD,
                          int* __restrict__ row_off, float* __restrict__ deg_in,
                          int* __restrict__ csr_src, int N) {
    __shared__ int cnt[256], off[256], cur[256];
    __shared__ unsigned eb[EDGE_CAP];
    int b = blockIdx.x, t = threadIdx.x;
    int lo = bsD[b], hi = bsD[b + 1], ne = hi - lo;
    bool fits = (ne <= EDGE_CAP);
    if (t < 256) cnt[t] = 0;
    __syncthreads();
    for (int i = t; i < ne; i += 1024) {
        unsigned v = packD[lo + i];
        if (fits) eb[i] = v;
        atomicAdd(&cnt[v >> 24], 1);
    }
    __syncthreads();
    if (t < 256) off[t] = cnt[t];
    __syncthreads();
    for (int o = 1; o < 256; o <<= 1) {
        int u = 0;
        if (t < 256 && t >= o) u = off[t - o];
        __syncthreads();
        if (t < 256) off[t] += u;
        __syncthreads();
    }
    if (t < 256) {
        int ex = off[t] - cnt[t];  // exclusive scan
        cur[t] = lo + ex;
        int node = b * 256 + t;
        if (node < N) {
            row_off[node] = lo + ex;
            deg_in[node] = (float)cnt[t];
        }
    }
    __syncthreads();
    for (int i = t; i < ne; i += 1024) {
        unsigned v = fits ? eb[i] : packD[lo + i];
        int pos = atomicAdd(&cur[v >> 24], 1);
        csr_src[pos] = (int)(v & 0xFFFFFFu);
    }
}

// pass E (src side): per-bin exact counts -> deg_out
__global__ void k_cnt_bin(const unsigned* __restrict__ packS, const int* __restrict__ bsS,
                          float* __restrict__ deg_out, int N) {
    __shared__ int cnt[256];
    int b = blockIdx.x, t = threadIdx.x;
    int lo = bsS[b], hi = bsS[b + 1];
    if (t < 256) cnt[t] = 0;
    __syncthreads();
    for (int i = lo + t; i < hi; i += 1024) atomicAdd(&cnt[packS[i] & 255], 1);
    __syncthreads();
    if (t < 256) {
        int node = b * 256 + t;
        if (node < N) deg_out[node] = (float)cnt[t];
    }
}

// ============ model kernels ============

// layer-1 transforms: h = [x, deg_in, deg_out] (N,3); A = h@Wl+bl, B = h@Wr+br
__global__ void k_xfrm1(const float* __restrict__ x, const float* __restrict__ deg_in,
                        const float* __restrict__ deg_out,
                        const float* __restrict__ Wl, const float* __restrict__ bl,
                        const float* __restrict__ Wr, const float* __restrict__ br,
                        float* __restrict__ A, float* __restrict__ B, int N) {
    int idx = blockIdx.x * blockDim.x + threadIdx.x;
    if (idx >= N * HID) return;
    int n = idx >> 6, c = idx & 63;
    float h0 = x[n], h1 = deg_in[n], h2 = deg_out[n];
    A[idx] = h0 * Wl[c] + h1 * Wl[HID + c] + h2 * Wl[2 * HID + c] + bl[c];
    B[idx] = h0 * Wr[c] + h1 * Wr[HID + c] + h2 * Wr[2 * HID + c] + br[c];
}

// Fused GATv2 layer: one wave per dst node, online softmax, no atomics.
template <bool TANH>
__global__ void k_gat_fused(const int* __restrict__ csr_src, const int* __restrict__ row_off,
                            const float* __restrict__ A, const float* __restrict__ B,
                            const float* __restrict__ aw, const float* __restrict__ bias,
                            float* __restrict__ out, int N) {
    int wid = (int)((blockIdx.x * (size_t)blockDim.x + threadIdx.x) >> 6);
    int lane = threadIdx.x & 63;
    if (wid >= N) return;
    int d = wid;
    float a_l = aw[lane];
    float xr = B[(size_t)d * HID + lane];

    // self loop seeds the online-softmax state
    float ar = A[(size_t)d * HID + lane];
    float v = ar + xr; v = v > 0.0f ? v : NEG_SLOPE * v;
    float t = v * a_l;
    #pragma unroll
    for (int o = 32; o; o >>= 1) t += __shfl_xor(t, o);
    float m = t;
    float denom = 1.0f;
    float acc = ar;

    int lo = row_off[d], hi = row_off[d + 1];
    int k = lo;
    for (; k + 1 < hi; k += 2) {
        int s0 = csr_src[k], s1 = csr_src[k + 1];
        float ar0 = A[(size_t)s0 * HID + lane];
        float ar1 = A[(size_t)s1 * HID + lane];
        float v0 = ar0 + xr; v0 = v0 > 0.0f ? v0 : NEG_SLOPE * v0;
        float v1 = ar1 + xr; v1 = v1 > 0.0f ? v1 : NEG_SLOPE * v1;
        float t0 = v0 * a_l, t1 = v1 * a_l;
        #pragma unroll
        for (int o = 32; o; o >>= 1) { t0 += __shfl_xor(t0, o); t1 += __shfl_xor(t1, o); }
        if (t0 > m) { float sc = __expf(m - t0); acc *= sc; denom *= sc; m = t0; }
        float w0 = __expf(t0 - m);
        denom += w0; acc = fmaf(w0, ar0, acc);
        if (t1 > m) { float sc = __expf(m - t1); acc *= sc; denom *= sc; m = t1; }
        float w1 = __expf(t1 - m);
        denom += w1; acc = fmaf(w1, ar1, acc);
    }
    if (k < hi) {
        int s0 = csr_src[k];
        float ar0 = A[(size_t)s0 * HID + lane];
        float v0 = ar0 + xr; v0 = v0 > 0.0f ? v0 : NEG_SLOPE * v0;
        float t0 = v0 * a_l;
        #pragma unroll
        for (int o = 32; o; o >>= 1) t0 += __shfl_xor(t0, o);
        if (t0 > m) { float sc = __expf(m - t0); acc *= sc; denom *= sc; m = t0; }
        float w0 = __expf(t0 - m);
        denom += w0; acc = fmaf(w0, ar0, acc);
    }

    float o = acc / denom + bias[lane];
    if (TANH) o = tanhf(o);
    out[(size_t)d * HID + lane] = o;
}

// layer-2 transforms: A = H@Wl2+bl2, B = H@Wr2+br2 (64x64 each)
__global__ void k_xfrm2(const float* __restrict__ H,
                        const float* __restrict__ Wl, const float* __restrict__ bl,
                        const float* __restrict__ Wr, const float* __restrict__ br,
                        float* __restrict__ A, float* __restrict__ B, int N) {
    int idx = blockIdx.x * blockDim.x + threadIdx.x;
    if (idx >= N * HID) return;
    int n = idx >> 6, c = idx & 63;
    const float* h = H + (size_t)n * HID;
    float sl = bl[c], sr = br[c];
    #pragma unroll 8
    for (int kk = 0; kk < HID; ++kk) {
        float hv = h[kk];
        sl += hv * Wl[kk * HID + c];
        sr += hv * Wr[kk * HID + c];
    }
    A[idx] = sl;
    B[idx] = sr;
}

// graph boundaries from sorted batch (no atomics)
__global__ void k_gbounds(const int* __restrict__ batch, int* __restrict__ gstart,
                          int* __restrict__ gend, int N) {
    int i = blockIdx.x * blockDim.x + threadIdx.x;
    if (i >= N) return;
    int g = batch[i];
    if (i == 0 || batch[i - 1] != g) gstart[g] = i;
    if (i == N - 1 || batch[i + 1] != g) gend[g] = i + 1;
}

// segment max pool: one wave per graph, coalesced, no atomics
__global__ void k_pool_seg(const float* __restrict__ C, const float* __restrict__ b2,
                           const int* __restrict__ gstart, const int* __restrict__ gend,
                           float* __restrict__ gout, int G) {
    int w = (int)((blockIdx.x * (size_t)blockDim.x + threadIdx.x) >> 6);
    int lane = threadIdx.x & 63;
    if (w >= G) return;
    float acc = -INFINITY;
    int lo = gstart[w], hi = gend[w];
    for (int i = lo; i < hi; ++i) acc = fmaxf(acc, C[(size_t)i * HID + lane]);
    gout[(size_t)w * HID + lane] = acc + b2[lane];
}

// out = g @ W3 + b3  [G,2]
__global__ void k_final(const float* __restrict__ gout, const float* __restrict__ W3,
                        const float* __restrict__ b3, float* __restrict__ out, int G) {
    int idx = blockIdx.x * blockDim.x + threadIdx.x;
    if (idx >= G * 2) return;
    int gi = idx >> 1, j = idx & 1;
    float sum = b3[j];
    #pragma unroll 8
    for (int kk = 0; kk < HID; ++kk) sum += gout[(size_t)gi * HID + kk] * W3[kk * 2 + j];
    out[idx] = sum;
}

extern "C" void kernel_launch(void* const* d_in, const int* in_sizes, int n_in,
                              void* d_out, int out_size, void* d_ws, size_t ws_size,
                              hipStream_t stream) {
    const float* x     = (const float*)d_in[0];
    const int*   ei    = (const int*)d_in[1];
    const int*   batch = (const int*)d_in[2];
    const float* Wl1 = (const float*)d_in[3];
    const float* bl1 = (const float*)d_in[4];
    const float* Wr1 = (const float*)d_in[5];
    const float* br1 = (const float*)d_in[6];
    const float* a1  = (const float*)d_in[7];
    const float* b1  = (const float*)d_in[8];
    const float* Wl2 = (const float*)d_in[9];
    const float* bl2 = (const float*)d_in[10];
    const float* Wr2 = (const float*)d_in[11];
    const float* br2 = (const float*)d_in[12];
    const float* a2  = (const float*)d_in[13];
    const float* b2  = (const float*)d_in[14];
    const float* W3  = (const float*)d_in[15];
    const float* b3  = (const float*)d_in[16];

    const int N = in_sizes[0];          // 100000
    const int E = in_sizes[1] / 2;      // 1600000
    const int G = out_size / 2;         // 1000
    const int NB = (N + 255) >> 8;      // 391 bins of 256 nodes
    const int NBLK = (E + BLK_E - 1) / BLK_E;  // 196 edge blocks

    // ---- workspace layout ----
    float* ws = (float*)d_ws;
    size_t off = 0;
    float* A  = ws + off; off += (size_t)N * HID;
    float* Bv = ws + off; off += (size_t)N * HID;
    float* C  = ws + off; off += (size_t)N * HID;   // sort temporaries overlay here
    int*   row_off = (int*)(ws + off); off += N + 1;
    int*   csr_src = (int*)(ws + off); off += E;
    float* deg_in  = ws + off; off += N;
    float* deg_out = ws + off; off += N;
    int*   bsS  = (int*)(ws + off); off += NB + 1;
    int*   bsD  = (int*)(ws + off); off += NB + 1;
    int*   totS = (int*)(ws + off); off += NB;
    int*   totD = (int*)(ws + off); off += NB;
    int*   gstart = (int*)(ws + off); off += G;
    int*   gend   = (int*)(ws + off); off += G;
    float* gout   = ws + off; off += (size_t)G * HID;

    // sort temporaries overlaid on C (dead until first k_gat_fused writes C)
    unsigned* packD = (unsigned*)C;
    unsigned* packS = packD + E;
    int* histS = (int*)(packS + E);
    int* histD = histS + (size_t)NB * NBLK;

    const int* src  = ei;
    const int* dstp = ei + E;

    const int BT = 256;
    dim3 blk(BT);
    int grid_nodeC = (N * HID + BT - 1) / BT;
    int grid_wavN  = (int)(((size_t)N * 64 + BT - 1) / BT);

    // ---- CSR build via counting sort (no global atomics) ----
    k_hist2<<<NBLK, 1024, 0, stream>>>(src, dstp, histS, histD, E, NB, NBLK);
    k_binscan<<<2 * NB, 256, 0, stream>>>(histS, histD, totS, totD, NB, NBLK);
    k_binoffset<<<1, 512, 0, stream>>>(totS, totD, bsS, bsD, NB, E, row_off, N);
    k_scatter_bins<<<NBLK, 1024, 0, stream>>>(src, dstp, histS, histD, bsS, bsD,
                                              packS, packD, E, NB, NBLK);
    k_csr_bin<<<NB, 1024, 0, stream>>>(packD, bsD, row_off, deg_in, csr_src, N);
    k_cnt_bin<<<NB, 1024, 0, stream>>>(packS, bsS, deg_out, N);

    // graph boundaries (for pool)
    hipMemsetAsync(gstart, 0, 2 * (size_t)G * sizeof(int), stream);
    k_gbounds<<<(N + BT - 1) / BT, blk, 0, stream>>>(batch, gstart, gend, N);

    // ---- layer 1 ----
    k_xfrm1<<<grid_nodeC, blk, 0, stream>>>(x, deg_in, deg_out, Wl1, bl1, Wr1, br1, A, Bv, N);
    k_gat_fused<true><<<grid_wavN, blk, 0, stream>>>(csr_src, row_off, A, Bv, a1, b1, C, N);

    // ---- layer 2 ----
    k_xfrm2<<<grid_nodeC, blk, 0, stream>>>(C, Wl2, bl2, Wr2, br2, A, Bv, N);
    k_gat_fused<false><<<grid_wavN, blk, 0, stream>>>(csr_src, row_off, A, Bv, a2, b2, C, N);

    // ---- pool + final linear ----
    k_pool_seg<<<(G * 64 + BT - 1) / BT, blk, 0, stream>>>(C, b2, gstart, gend, gout, G);
    k_final<<<(G * 2 + BT - 1) / BT, blk, 0, stream>>>(gout, W3, b3, (float*)d_out, G);
}

// Round 5
// 279.595 us; speedup vs baseline: 6.7960x; 1.8180x over previous
//
#include <hip/hip_runtime.h>
#include <hip/hip_bf16.h>

#define HID 64
#define NEG_SLOPE 0.2f
#define BLK_E 8192        // edges per block in binning passes
#define EDGE_CAP 6144     // LDS edge cache per bin

// ============ counting-sort CSR build (no global atomics) ============

__global__ void k_hist2(const int* __restrict__ src, const int* __restrict__ dst,
                        int* __restrict__ histS, int* __restrict__ histD,
                        int E, int NB, int NBLK) {
    __shared__ int hs[512], hd[512];
    int t = threadIdx.x, blk = blockIdx.x;
    for (int b = t; b < NB; b += 1024) { hs[b] = 0; hd[b] = 0; }
    __syncthreads();
    int base = blk * BLK_E;
    #pragma unroll
    for (int k = 0; k < BLK_E / 1024; ++k) {
        int i = base + k * 1024 + t;
        if (i < E) {
            atomicAdd(&hs[src[i] >> 8], 1);
            atomicAdd(&hd[dst[i] >> 8], 1);
        }
    }
    __syncthreads();
    for (int b = t; b < NB; b += 1024) {
        histS[b * NBLK + blk] = hs[b];
        histD[b * NBLK + blk] = hd[b];
    }
}

__global__ void k_binscan(int* __restrict__ histS, int* __restrict__ histD,
                          int* __restrict__ totS, int* __restrict__ totD,
                          int NB, int NBLK) {
    __shared__ int s[256];
    int b = blockIdx.x;
    int* hist = histS; int* tot = totS;
    if (b >= NB) { b -= NB; hist = histD; tot = totD; }
    int t = threadIdx.x;
    int v = (t < NBLK) ? hist[b * NBLK + t] : 0;
    s[t] = v;
    __syncthreads();
    for (int o = 1; o < 256; o <<= 1) {
        int u = (t >= o) ? s[t - o] : 0;
        __syncthreads();
        s[t] += u;
        __syncthreads();
    }
    if (t < NBLK) hist[b * NBLK + t] = s[t] - v;
    if (t == 255) tot[b] = s[255];
}

__global__ void k_binoffset(const int* __restrict__ totS, const int* __restrict__ totD,
                            int* __restrict__ bsS, int* __restrict__ bsD,
                            int NB, int E, int* __restrict__ row_off, int N) {
    __shared__ int s[512];
    int t = threadIdx.x;
    int v = (t < NB) ? totS[t] : 0;
    s[t] = v; __syncthreads();
    for (int o = 1; o < 512; o <<= 1) {
        int u = (t >= o) ? s[t - o] : 0;
        __syncthreads(); s[t] += u; __syncthreads();
    }
    if (t < NB) bsS[t] = s[t] - v;
    if (t == 0) bsS[NB] = E;
    __syncthreads();
    v = (t < NB) ? totD[t] : 0;
    s[t] = v; __syncthreads();
    for (int o = 1; o < 512; o <<= 1) {
        int u = (t >= o) ? s[t - o] : 0;
        __syncthreads(); s[t] += u; __syncthreads();
    }
    if (t < NB) bsD[t] = s[t] - v;
    if (t == 0) { bsD[NB] = E; row_off[N] = E; }
}

__global__ void k_scatter_bins(const int* __restrict__ src, const int* __restrict__ dst,
                               const int* __restrict__ histS, const int* __restrict__ histD,
                               const int* __restrict__ bsS, const int* __restrict__ bsD,
                               unsigned* __restrict__ packS, unsigned* __restrict__ packD,
                               int E, int NB, int NBLK) {
    __shared__ int baseS[512], baseD[512];
    int t = threadIdx.x, blk = blockIdx.x;
    for (int b = t; b < NB; b += 1024) {
        baseS[b] = bsS[b] + histS[b * NBLK + blk];
        baseD[b] = bsD[b] + histD[b * NBLK + blk];
    }
    __syncthreads();
    int base = blk * BLK_E;
    #pragma unroll
    for (int k = 0; k < BLK_E / 1024; ++k) {
        int i = base + k * 1024 + t;
        if (i < E) {
            int sv = src[i], dv = dst[i];
            int pD = atomicAdd(&baseD[dv >> 8], 1);
            packD[pD] = ((unsigned)(dv & 255) << 24) | (unsigned)sv;
            int pS = atomicAdd(&baseS[sv >> 8], 1);
            packS[pS] = (unsigned)(sv & 255);
        }
    }
}

__global__ void k_csr_bin(const unsigned* __restrict__ packD, const int* __restrict__ bsD,
                          int* __restrict__ row_off, float* __restrict__ deg_in,
                          int* __restrict__ csr_src, int N) {
    __shared__ int cnt[256], off[256], cur[256];
    __shared__ unsigned eb[EDGE_CAP];
    int b = blockIdx.x, t = threadIdx.x;
    int lo = bsD[b], hi = bsD[b + 1], ne = hi - lo;
    bool fits = (ne <= EDGE_CAP);
    if (t < 256) cnt[t] = 0;
    __syncthreads();
    for (int i = t; i < ne; i += 1024) {
        unsigned v = packD[lo + i];
        if (fits) eb[i] = v;
        atomicAdd(&cnt[v >> 24], 1);
    }
    __syncthreads();
    if (t < 256) off[t] = cnt[t];
    __syncthreads();
    for (int o = 1; o < 256; o <<= 1) {
        int u = 0;
        if (t < 256 && t >= o) u = off[t - o];
        __syncthreads();
        if (t < 256) off[t] += u;
        __syncthreads();
    }
    if (t < 256) {
        int ex = off[t] - cnt[t];
        cur[t] = lo + ex;
        int node = b * 256 + t;
        if (node < N) {
            row_off[node] = lo + ex;
            deg_in[node] = (float)cnt[t];
        }
    }
    __syncthreads();
    for (int i = t; i < ne; i += 1024) {
        unsigned v = fits ? eb[i] : packD[lo + i];
        int pos = atomicAdd(&cur[v >> 24], 1);
        csr_src[pos] = (int)(v & 0xFFFFFFu);
    }
}

__global__ void k_cnt_bin(const unsigned* __restrict__ packS, const int* __restrict__ bsS,
                          float* __restrict__ deg_out, int N) {
    __shared__ int cnt[256];
    int b = blockIdx.x, t = threadIdx.x;
    int lo = bsS[b], hi = bsS[b + 1];
    if (t < 256) cnt[t] = 0;
    __syncthreads();
    for (int i = lo + t; i < hi; i += 1024) atomicAdd(&cnt[packS[i] & 255], 1);
    __syncthreads();
    if (t < 256) {
        int node = b * 256 + t;
        if (node < N) deg_out[node] = (float)cnt[t];
    }
}

// ============ model kernels ============

__global__ void k_xfrm1(const float* __restrict__ x, const float* __restrict__ deg_in,
                        const float* __restrict__ deg_out,
                        const float* __restrict__ Wl, const float* __restrict__ bl,
                        const float* __restrict__ Wr, const float* __restrict__ br,
                        float* __restrict__ A, float* __restrict__ B, int N) {
    int idx = blockIdx.x * blockDim.x + threadIdx.x;
    if (idx >= N * HID) return;
    int n = idx >> 6, c = idx & 63;
    float h0 = x[n], h1 = deg_in[n], h2 = deg_out[n];
    A[idx] = h0 * Wl[c] + h1 * Wl[HID + c] + h2 * Wl[2 * HID + c] + bl[c];
    B[idx] = h0 * Wr[c] + h1 * Wr[HID + c] + h2 * Wr[2 * HID + c] + br[c];
}

// Fused GATv2 layer: 16 lanes per dst node (float4 = 64 ch), online softmax, no atomics.
template <bool TANH>
__global__ void k_gat_fused(const int* __restrict__ csr_src, const int* __restrict__ row_off,
                            const float* __restrict__ A, const float* __restrict__ B,
                            const float* __restrict__ aw, const float* __restrict__ bias,
                            float* __restrict__ out, int N) {
    int tid = blockIdx.x * blockDim.x + threadIdx.x;
    int d = tid >> 4;            // one dst node per 16-lane group
    int gl = threadIdx.x & 15;   // lane within group
    if (d >= N) return;

    const float4* A4 = (const float4*)A;
    float4 awv = ((const float4*)aw)[gl];
    float4 xr  = ((const float4*)B)[(size_t)d * 16 + gl];

    // self loop seeds the online-softmax state
    float4 as = A4[(size_t)d * 16 + gl];
    float4 v;
    v.x = fmaxf(as.x + xr.x, NEG_SLOPE * (as.x + xr.x));
    v.y = fmaxf(as.y + xr.y, NEG_SLOPE * (as.y + xr.y));
    v.z = fmaxf(as.z + xr.z, NEG_SLOPE * (as.z + xr.z));
    v.w = fmaxf(as.w + xr.w, NEG_SLOPE * (as.w + xr.w));
    float t = fmaf(v.x, awv.x, fmaf(v.y, awv.y, fmaf(v.z, awv.z, v.w * awv.w)));
    #pragma unroll
    for (int o = 1; o < 16; o <<= 1) t += __shfl_xor(t, o);
    float m = t;
    float denom = 1.0f;
    float4 acc = as;

    int lo = row_off[d], hi = row_off[d + 1];
    int k = lo;
    for (; k + 1 < hi; k += 2) {
        int s0 = csr_src[k], s1 = csr_src[k + 1];
        float4 a0 = A4[(size_t)s0 * 16 + gl];
        float4 a1 = A4[(size_t)s1 * 16 + gl];
        float4 v0, v1;
        v0.x = fmaxf(a0.x + xr.x, NEG_SLOPE * (a0.x + xr.x));
        v0.y = fmaxf(a0.y + xr.y, NEG_SLOPE * (a0.y + xr.y));
        v0.z = fmaxf(a0.z + xr.z, NEG_SLOPE * (a0.z + xr.z));
        v0.w = fmaxf(a0.w + xr.w, NEG_SLOPE * (a0.w + xr.w));
        v1.x = fmaxf(a1.x + xr.x, NEG_SLOPE * (a1.x + xr.x));
        v1.y = fmaxf(a1.y + xr.y, NEG_SLOPE * (a1.y + xr.y));
        v1.z = fmaxf(a1.z + xr.z, NEG_SLOPE * (a1.z + xr.z));
        v1.w = fmaxf(a1.w + xr.w, NEG_SLOPE * (a1.w + xr.w));
        float t0 = fmaf(v0.x, awv.x, fmaf(v0.y, awv.y, fmaf(v0.z, awv.z, v0.w * awv.w)));
        float t1 = fmaf(v1.x, awv.x, fmaf(v1.y, awv.y, fmaf(v1.z, awv.z, v1.w * awv.w)));
        #pragma unroll
        for (int o = 1; o < 16; o <<= 1) { t0 += __shfl_xor(t0, o); t1 += __shfl_xor(t1, o); }
        if (t0 > m) {
            float sc = __expf(m - t0);
            acc.x *= sc; acc.y *= sc; acc.z *= sc; acc.w *= sc;
            denom *= sc; m = t0;
        }
        float w0 = __expf(t0 - m);
        denom += w0;
        acc.x = fmaf(w0, a0.x, acc.x); acc.y = fmaf(w0, a0.y, acc.y);
        acc.z = fmaf(w0, a0.z, acc.z); acc.w = fmaf(w0, a0.w, acc.w);
        if (t1 > m) {
            float sc = __expf(m - t1);
            acc.x *= sc; acc.y *= sc; acc.z *= sc; acc.w *= sc;
            denom *= sc; m = t1;
        }
        float w1 = __expf(t1 - m);
        denom += w1;
        acc.x = fmaf(w1, a1.x, acc.x); acc.y = fmaf(w1, a1.y, acc.y);
        acc.z = fmaf(w1, a1.z, acc.z); acc.w = fmaf(w1, a1.w, acc.w);
    }
    if (k < hi) {
        int s0 = csr_src[k];
        float4 a0 = A4[(size_t)s0 * 16 + gl];
        float4 v0;
        v0.x = fmaxf(a0.x + xr.x, NEG_SLOPE * (a0.x + xr.x));
        v0.y = fmaxf(a0.y + xr.y, NEG_SLOPE * (a0.y + xr.y));
        v0.z = fmaxf(a0.z + xr.z, NEG_SLOPE * (a0.z + xr.z));
        v0.w = fmaxf(a0.w + xr.w, NEG_SLOPE * (a0.w + xr.w));
        float t0 = fmaf(v0.x, awv.x, fmaf(v0.y, awv.y, fmaf(v0.z, awv.z, v0.w * awv.w)));
        #pragma unroll
        for (int o = 1; o < 16; o <<= 1) t0 += __shfl_xor(t0, o);
        if (t0 > m) {
            float sc = __expf(m - t0);
            acc.x *= sc; acc.y *= sc; acc.z *= sc; acc.w *= sc;
            denom *= sc; m = t0;
        }
        float w0 = __expf(t0 - m);
        denom += w0;
        acc.x = fmaf(w0, a0.x, acc.x); acc.y = fmaf(w0, a0.y, acc.y);
        acc.z = fmaf(w0, a0.z, acc.z); acc.w = fmaf(w0, a0.w, acc.w);
    }

    float4 bv = ((const float4*)bias)[gl];
    float inv = 1.0f / denom;
    float4 o4;
    o4.x = acc.x * inv + bv.x;
    o4.y = acc.y * inv + bv.y;
    o4.z = acc.z * inv + bv.z;
    o4.w = acc.w * inv + bv.w;
    if (TANH) {
        o4.x = tanhf(o4.x); o4.y = tanhf(o4.y); o4.z = tanhf(o4.z); o4.w = tanhf(o4.w);
    }
    ((float4*)out)[(size_t)d * 16 + gl] = o4;
}

// layer-2 transforms, LDS-tiled: block = 512 threads (8 waves) x 64 nodes.
// wave w computes channels [w*8, w*8+8) for 64 nodes (lane = node).
__global__ __launch_bounds__(512) void k_xfrm2(
        const float* __restrict__ H,
        const float* __restrict__ Wl, const float* __restrict__ bl,
        const float* __restrict__ Wr, const float* __restrict__ br,
        float* __restrict__ A, float* __restrict__ B, int N) {
    __shared__ float wls[4096];       // [kk][c]
    __shared__ float wrs[4096];
    __shared__ float hst[64 * 66];    // transposed: [kk][node], pad 66 -> 2-way free
    int t = threadIdx.x;
    int base = blockIdx.x * 64;

    // stage W (1024 float4 each)
    ((float4*)wls)[t * 2]     = ((const float4*)Wl)[t * 2];
    ((float4*)wls)[t * 2 + 1] = ((const float4*)Wl)[t * 2 + 1];
    ((float4*)wrs)[t * 2]     = ((const float4*)Wr)[t * 2];
    ((float4*)wrs)[t * 2 + 1] = ((const float4*)Wr)[t * 2 + 1];

    // stage h tile, transposed (coalesced global reads)
    #pragma unroll
    for (int u = 0; u < 2; ++u) {
        int j = t * 2 + u;            // float4 index in [64 nodes][16 f4]
        int nd = j >> 4, c4 = j & 15;
        int node = base + nd;
        float4 hv = (node < N) ? ((const float4*)H)[(size_t)node * 16 + c4]
                               : make_float4(0.f, 0.f, 0.f, 0.f);
        hst[(c4 * 4 + 0) * 66 + nd] = hv.x;
        hst[(c4 * 4 + 1) * 66 + nd] = hv.y;
        hst[(c4 * 4 + 2) * 66 + nd] = hv.z;
        hst[(c4 * 4 + 3) * 66 + nd] = hv.w;
    }
    __syncthreads();

    int w = t >> 6, l = t & 63;
    float acL[8] = {0, 0, 0, 0, 0, 0, 0, 0};
    float acR[8] = {0, 0, 0, 0, 0, 0, 0, 0};
    #pragma unroll 4
    for (int kk = 0; kk < 64; ++kk) {
        float hv = hst[kk * 66 + l];
        const float4* wl4 = (const float4*)&wls[kk * 64 + w * 8];
        const float4* wr4 = (const float4*)&wrs[kk * 64 + w * 8];
        float4 w0 = wl4[0], w1 = wl4[1];
        float4 r0 = wr4[0], r1 = wr4[1];
        acL[0] = fmaf(hv, w0.x, acL[0]); acL[1] = fmaf(hv, w0.y, acL[1]);
        acL[2] = fmaf(hv, w0.z, acL[2]); acL[3] = fmaf(hv, w0.w, acL[3]);
        acL[4] = fmaf(hv, w1.x, acL[4]); acL[5] = fmaf(hv, w1.y, acL[5]);
        acL[6] = fmaf(hv, w1.z, acL[6]); acL[7] = fmaf(hv, w1.w, acL[7]);
        acR[0] = fmaf(hv, r0.x, acR[0]); acR[1] = fmaf(hv, r0.y, acR[1]);
        acR[2] = fmaf(hv, r0.z, acR[2]); acR[3] = fmaf(hv, r0.w, acR[3]);
        acR[4] = fmaf(hv, r1.x, acR[4]); acR[5] = fmaf(hv, r1.y, acR[5]);
        acR[6] = fmaf(hv, r1.z, acR[6]); acR[7] = fmaf(hv, r1.w, acR[7]);
    }

    int node = base + l;
    if (node < N) {
        float4 bl0 = ((const float4*)bl)[w * 2], bl1 = ((const float4*)bl)[w * 2 + 1];
        float4 br0 = ((const float4*)br)[w * 2], br1 = ((const float4*)br)[w * 2 + 1];
        float4 o0 = make_float4(acL[0] + bl0.x, acL[1] + bl0.y, acL[2] + bl0.z, acL[3] + bl0.w);
        float4 o1 = make_float4(acL[4] + bl1.x, acL[5] + bl1.y, acL[6] + bl1.z, acL[7] + bl1.w);
        ((float4*)A)[(size_t)node * 16 + w * 2]     = o0;
        ((float4*)A)[(size_t)node * 16 + w * 2 + 1] = o1;
        float4 p0 = make_float4(acR[0] + br0.x, acR[1] + br0.y, acR[2] + br0.z, acR[3] + br0.w);
        float4 p1 = make_float4(acR[4] + br1.x, acR[5] + br1.y, acR[6] + br1.z, acR[7] + br1.w);
        ((float4*)B)[(size_t)node * 16 + w * 2]     = p0;
        ((float4*)B)[(size_t)node * 16 + w * 2 + 1] = p1;
    }
}

__global__ void k_gbounds(const int* __restrict__ batch, int* __restrict__ gstart,
                          int* __restrict__ gend, int N) {
    int i = blockIdx.x * blockDim.x + threadIdx.x;
    if (i >= N) return;
    int g = batch[i];
    if (i == 0 || batch[i - 1] != g) gstart[g] = i;
    if (i == N - 1 || batch[i + 1] != g) gend[g] = i + 1;
}

__global__ void k_pool_seg(const float* __restrict__ C, const float* __restrict__ b2,
                           const int* __restrict__ gstart, const int* __restrict__ gend,
                           float* __restrict__ gout, int G) {
    int w = (int)((blockIdx.x * (size_t)blockDim.x + threadIdx.x) >> 6);
    int lane = threadIdx.x & 63;
    if (w >= G) return;
    float acc = -INFINITY;
    int lo = gstart[w], hi = gend[w];
    for (int i = lo; i < hi; ++i) acc = fmaxf(acc, C[(size_t)i * HID + lane]);
    gout[(size_t)w * HID + lane] = acc + b2[lane];
}

__global__ void k_final(const float* __restrict__ gout, const float* __restrict__ W3,
                        const float* __restrict__ b3, float* __restrict__ out, int G) {
    int idx = blockIdx.x * blockDim.x + threadIdx.x;
    if (idx >= G * 2) return;
    int gi = idx >> 1, j = idx & 1;
    float sum = b3[j];
    #pragma unroll 8
    for (int kk = 0; kk < HID; ++kk) sum += gout[(size_t)gi * HID + kk] * W3[kk * 2 + j];
    out[idx] = sum;
}

extern "C" void kernel_launch(void* const* d_in, const int* in_sizes, int n_in,
                              void* d_out, int out_size, void* d_ws, size_t ws_size,
                              hipStream_t stream) {
    const float* x     = (const float*)d_in[0];
    const int*   ei    = (const int*)d_in[1];
    const int*   batch = (const int*)d_in[2];
    const float* Wl1 = (const float*)d_in[3];
    const float* bl1 = (const float*)d_in[4];
    const float* Wr1 = (const float*)d_in[5];
    const float* br1 = (const float*)d_in[6];
    const float* a1  = (const float*)d_in[7];
    const float* b1  = (const float*)d_in[8];
    const float* Wl2 = (const float*)d_in[9];
    const float* bl2 = (const float*)d_in[10];
    const float* Wr2 = (const float*)d_in[11];
    const float* br2 = (const float*)d_in[12];
    const float* a2  = (const float*)d_in[13];
    const float* b2  = (const float*)d_in[14];
    const float* W3  = (const float*)d_in[15];
    const float* b3  = (const float*)d_in[16];

    const int N = in_sizes[0];          // 100000
    const int E = in_sizes[1] / 2;      // 1600000
    const int G = out_size / 2;         // 1000
    const int NB = (N + 255) >> 8;
    const int NBLK = (E + BLK_E - 1) / BLK_E;

    // ---- workspace layout ----
    float* ws = (float*)d_ws;
    size_t off = 0;
    float* A  = ws + off; off += (size_t)N * HID;
    float* Bv = ws + off; off += (size_t)N * HID;
    float* C  = ws + off; off += (size_t)N * HID;   // sort temporaries overlay here
    int*   row_off = (int*)(ws + off); off += N + 1;
    int*   csr_src = (int*)(ws + off); off += E;
    float* deg_in  = ws + off; off += N;
    float* deg_out = ws + off; off += N;
    int*   bsS  = (int*)(ws + off); off += NB + 1;
    int*   bsD  = (int*)(ws + off); off += NB + 1;
    int*   totS = (int*)(ws + off); off += NB;
    int*   totD = (int*)(ws + off); off += NB;
    int*   gstart = (int*)(ws + off); off += G;
    int*   gend   = (int*)(ws + off); off += G;
    float* gout   = ws + off; off += (size_t)G * HID;

    unsigned* packD = (unsigned*)C;
    unsigned* packS = packD + E;
    int* histS = (int*)(packS + E);
    int* histD = histS + (size_t)NB * NBLK;

    const int* src  = ei;
    const int* dstp = ei + E;

    const int BT = 256;
    dim3 blk(BT);
    int grid_nodeC = (N * HID + BT - 1) / BT;
    int grid_g16   = (int)(((size_t)N * 16 + BT - 1) / BT);
    int grid_x2    = (N + 63) / 64;

    // ---- CSR build via counting sort (no global atomics) ----
    k_hist2<<<NBLK, 1024, 0, stream>>>(src, dstp, histS, histD, E, NB, NBLK);
    k_binscan<<<2 * NB, 256, 0, stream>>>(histS, histD, totS, totD, NB, NBLK);
    k_binoffset<<<1, 512, 0, stream>>>(totS, totD, bsS, bsD, NB, E, row_off, N);
    k_scatter_bins<<<NBLK, 1024, 0, stream>>>(src, dstp, histS, histD, bsS, bsD,
                                              packS, packD, E, NB, NBLK);
    k_csr_bin<<<NB, 1024, 0, stream>>>(packD, bsD, row_off, deg_in, csr_src, N);
    k_cnt_bin<<<NB, 1024, 0, stream>>>(packS, bsS, deg_out, N);

    hipMemsetAsync(gstart, 0, 2 * (size_t)G * sizeof(int), stream);
    k_gbounds<<<(N + BT - 1) / BT, blk, 0, stream>>>(batch, gstart, gend, N);

    // ---- layer 1 ----
    k_xfrm1<<<grid_nodeC, blk, 0, stream>>>(x, deg_in, deg_out, Wl1, bl1, Wr1, br1, A, Bv, N);
    k_gat_fused<true><<<grid_g16, blk, 0, stream>>>(csr_src, row_off, A, Bv, a1, b1, C, N);

    // ---- layer 2 ----
    k_xfrm2<<<grid_x2, 512, 0, stream>>>(C, Wl2, bl2, Wr2, br2, A, Bv, N);
    k_gat_fused<false><<<grid_g16, blk, 0, stream>>>(csr_src, row_off, A, Bv, a2, b2, C, N);

    // ---- pool + final linear ----
    k_pool_seg<<<(G * 64 + BT - 1) / BT, blk, 0, stream>>>(C, b2, gstart, gend, gout, G);
    k_final<<<(G * 2 + BT - 1) / BT, blk, 0, stream>>>(gout, W3, b3, (float*)d_out, G);
}

// Round 6
// 247.156 us; speedup vs baseline: 7.6880x; 1.1312x over previous
//
#include <hip/hip_runtime.h>
#include <hip/hip_bf16.h>
#include <hip/hip_fp16.h>

#define HID 64
#define NEG_SLOPE 0.2f
#define BLK_E 8192        // edges per block in binning passes
#define EDGE_CAP 6144     // LDS edge cache per bin

// ============ counting-sort CSR build (no global atomics) ============

__global__ void k_hist2(const int* __restrict__ src, const int* __restrict__ dst,
                        int* __restrict__ histS, int* __restrict__ histD,
                        int E, int NB, int NBLK) {
    __shared__ int hs[512], hd[512];
    int t = threadIdx.x, blk = blockIdx.x;
    for (int b = t; b < NB; b += 1024) { hs[b] = 0; hd[b] = 0; }
    __syncthreads();
    int base = blk * BLK_E;
    #pragma unroll
    for (int k = 0; k < BLK_E / 1024; ++k) {
        int i = base + k * 1024 + t;
        if (i < E) {
            atomicAdd(&hs[src[i] >> 8], 1);
            atomicAdd(&hd[dst[i] >> 8], 1);
        }
    }
    __syncthreads();
    for (int b = t; b < NB; b += 1024) {
        histS[b * NBLK + blk] = hs[b];
        histD[b * NBLK + blk] = hd[b];
    }
}

__global__ void k_binscan(int* __restrict__ histS, int* __restrict__ histD,
                          int* __restrict__ totS, int* __restrict__ totD,
                          int NB, int NBLK) {
    __shared__ int s[256];
    int b = blockIdx.x;
    int* hist = histS; int* tot = totS;
    if (b >= NB) { b -= NB; hist = histD; tot = totD; }
    int t = threadIdx.x;
    int v = (t < NBLK) ? hist[b * NBLK + t] : 0;
    s[t] = v;
    __syncthreads();
    for (int o = 1; o < 256; o <<= 1) {
        int u = (t >= o) ? s[t - o] : 0;
        __syncthreads();
        s[t] += u;
        __syncthreads();
    }
    if (t < NBLK) hist[b * NBLK + t] = s[t] - v;
    if (t == 255) tot[b] = s[255];
}

__global__ void k_binoffset(const int* __restrict__ totS, const int* __restrict__ totD,
                            int* __restrict__ bsS, int* __restrict__ bsD,
                            int NB, int E, int* __restrict__ row_off, int N) {
    __shared__ int s[512];
    int t = threadIdx.x;
    int v = (t < NB) ? totS[t] : 0;
    s[t] = v; __syncthreads();
    for (int o = 1; o < 512; o <<= 1) {
        int u = (t >= o) ? s[t - o] : 0;
        __syncthreads(); s[t] += u; __syncthreads();
    }
    if (t < NB) bsS[t] = s[t] - v;
    if (t == 0) bsS[NB] = E;
    __syncthreads();
    v = (t < NB) ? totD[t] : 0;
    s[t] = v; __syncthreads();
    for (int o = 1; o < 512; o <<= 1) {
        int u = (t >= o) ? s[t - o] : 0;
        __syncthreads(); s[t] += u; __syncthreads();
    }
    if (t < NB) bsD[t] = s[t] - v;
    if (t == 0) { bsD[NB] = E; row_off[N] = E; }
}

__global__ void k_scatter_bins(const int* __restrict__ src, const int* __restrict__ dst,
                               const int* __restrict__ histS, const int* __restrict__ histD,
                               const int* __restrict__ bsS, const int* __restrict__ bsD,
                               unsigned* __restrict__ packS, unsigned* __restrict__ packD,
                               int E, int NB, int NBLK) {
    __shared__ int baseS[512], baseD[512];
    int t = threadIdx.x, blk = blockIdx.x;
    for (int b = t; b < NB; b += 1024) {
        baseS[b] = bsS[b] + histS[b * NBLK + blk];
        baseD[b] = bsD[b] + histD[b * NBLK + blk];
    }
    __syncthreads();
    int base = blk * BLK_E;
    #pragma unroll
    for (int k = 0; k < BLK_E / 1024; ++k) {
        int i = base + k * 1024 + t;
        if (i < E) {
            int sv = src[i], dv = dst[i];
            int pD = atomicAdd(&baseD[dv >> 8], 1);
            packD[pD] = ((unsigned)(dv & 255) << 24) | (unsigned)sv;
            int pS = atomicAdd(&baseS[sv >> 8], 1);
            packS[pS] = (unsigned)(sv & 255);
        }
    }
}

__global__ void k_csr_bin(const unsigned* __restrict__ packD, const int* __restrict__ bsD,
                          int* __restrict__ row_off, float* __restrict__ deg_in,
                          int* __restrict__ csr_src, int N) {
    __shared__ int cnt[256], off[256], cur[256];
    __shared__ unsigned eb[EDGE_CAP];
    int b = blockIdx.x, t = threadIdx.x;
    int lo = bsD[b], hi = bsD[b + 1], ne = hi - lo;
    bool fits = (ne <= EDGE_CAP);
    if (t < 256) cnt[t] = 0;
    __syncthreads();
    for (int i = t; i < ne; i += 1024) {
        unsigned v = packD[lo + i];
        if (fits) eb[i] = v;
        atomicAdd(&cnt[v >> 24], 1);
    }
    __syncthreads();
    if (t < 256) off[t] = cnt[t];
    __syncthreads();
    for (int o = 1; o < 256; o <<= 1) {
        int u = 0;
        if (t < 256 && t >= o) u = off[t - o];
        __syncthreads();
        if (t < 256) off[t] += u;
        __syncthreads();
    }
    if (t < 256) {
        int ex = off[t] - cnt[t];
        cur[t] = lo + ex;
        int node = b * 256 + t;
        if (node < N) {
            row_off[node] = lo + ex;
            deg_in[node] = (float)cnt[t];
        }
    }
    __syncthreads();
    for (int i = t; i < ne; i += 1024) {
        unsigned v = fits ? eb[i] : packD[lo + i];
        int pos = atomicAdd(&cur[v >> 24], 1);
        csr_src[pos] = (int)(v & 0xFFFFFFu);
    }
}

__global__ void k_cnt_bin(const unsigned* __restrict__ packS, const int* __restrict__ bsS,
                          float* __restrict__ deg_out, int N) {
    __shared__ int cnt[256];
    int b = blockIdx.x, t = threadIdx.x;
    int lo = bsS[b], hi = bsS[b + 1];
    if (t < 256) cnt[t] = 0;
    __syncthreads();
    for (int i = lo + t; i < hi; i += 1024) atomicAdd(&cnt[packS[i] & 255], 1);
    __syncthreads();
    if (t < 256) {
        int node = b * 256 + t;
        if (node < N) deg_out[node] = (float)cnt[t];
    }
}

// ============ model kernels ============

// decode 4 packed halves (uint2) -> float4
__device__ __forceinline__ float4 h4f(uint2 r) {
    __half2 p0 = __builtin_bit_cast(__half2, r.x);
    __half2 p1 = __builtin_bit_cast(__half2, r.y);
    float2 q0 = __half22float2(p0);
    float2 q1 = __half22float2(p1);
    return make_float4(q0.x, q0.y, q1.x, q1.y);
}

__global__ void k_xfrm1(const float* __restrict__ x, const float* __restrict__ deg_in,
                        const float* __restrict__ deg_out,
                        const float* __restrict__ Wl, const float* __restrict__ bl,
                        const float* __restrict__ Wr, const float* __restrict__ br,
                        __half* __restrict__ A, __half* __restrict__ B, int N) {
    int idx = blockIdx.x * blockDim.x + threadIdx.x;
    if (idx >= N * HID) return;
    int n = idx >> 6, c = idx & 63;
    float h0 = x[n], h1 = deg_in[n], h2 = deg_out[n];
    A[idx] = __float2half(h0 * Wl[c] + h1 * Wl[HID + c] + h2 * Wl[2 * HID + c] + bl[c]);
    B[idx] = __float2half(h0 * Wr[c] + h1 * Wr[HID + c] + h2 * Wr[2 * HID + c] + br[c]);
}

// Fused GATv2 layer: 16 lanes per dst node, fp16 table gather, online softmax, no atomics.
template <bool TANH>
__global__ void k_gat_fused(const int* __restrict__ csr_src, const int* __restrict__ row_off,
                            const __half* __restrict__ Ah, const __half* __restrict__ Bh,
                            const float* __restrict__ aw, const float* __restrict__ bias,
                            float* __restrict__ out, int N) {
    int tid = blockIdx.x * blockDim.x + threadIdx.x;
    int d = tid >> 4;            // one dst node per 16-lane group
    int gl = threadIdx.x & 15;   // lane within group
    if (d >= N) return;

    const uint2* A2 = (const uint2*)Ah;
    const uint2* B2 = (const uint2*)Bh;
    float4 awv = ((const float4*)aw)[gl];
    float4 xr = h4f(B2[(size_t)d * 16 + gl]);

    // self loop seeds the online-softmax state
    float4 as = h4f(A2[(size_t)d * 16 + gl]);
    float4 v;
    v.x = as.x + xr.x; v.x = fmaxf(v.x, NEG_SLOPE * v.x);
    v.y = as.y + xr.y; v.y = fmaxf(v.y, NEG_SLOPE * v.y);
    v.z = as.z + xr.z; v.z = fmaxf(v.z, NEG_SLOPE * v.z);
    v.w = as.w + xr.w; v.w = fmaxf(v.w, NEG_SLOPE * v.w);
    float t = fmaf(v.x, awv.x, fmaf(v.y, awv.y, fmaf(v.z, awv.z, v.w * awv.w)));
    #pragma unroll
    for (int o = 1; o < 16; o <<= 1) t += __shfl_xor(t, o);
    float m = t;
    float denom = 1.0f;
    float4 acc = as;

    int lo = row_off[d], hi = row_off[d + 1];
    int k = lo;
    for (; k + 1 < hi; k += 2) {
        int s0 = csr_src[k], s1 = csr_src[k + 1];
        float4 a0 = h4f(A2[(size_t)s0 * 16 + gl]);
        float4 a1 = h4f(A2[(size_t)s1 * 16 + gl]);
        float4 v0, v1;
        v0.x = a0.x + xr.x; v0.x = fmaxf(v0.x, NEG_SLOPE * v0.x);
        v0.y = a0.y + xr.y; v0.y = fmaxf(v0.y, NEG_SLOPE * v0.y);
        v0.z = a0.z + xr.z; v0.z = fmaxf(v0.z, NEG_SLOPE * v0.z);
        v0.w = a0.w + xr.w; v0.w = fmaxf(v0.w, NEG_SLOPE * v0.w);
        v1.x = a1.x + xr.x; v1.x = fmaxf(v1.x, NEG_SLOPE * v1.x);
        v1.y = a1.y + xr.y; v1.y = fmaxf(v1.y, NEG_SLOPE * v1.y);
        v1.z = a1.z + xr.z; v1.z = fmaxf(v1.z, NEG_SLOPE * v1.z);
        v1.w = a1.w + xr.w; v1.w = fmaxf(v1.w, NEG_SLOPE * v1.w);
        float t0 = fmaf(v0.x, awv.x, fmaf(v0.y, awv.y, fmaf(v0.z, awv.z, v0.w * awv.w)));
        float t1 = fmaf(v1.x, awv.x, fmaf(v1.y, awv.y, fmaf(v1.z, awv.z, v1.w * awv.w)));
        #pragma unroll
        for (int o = 1; o < 16; o <<= 1) { t0 += __shfl_xor(t0, o); t1 += __shfl_xor(t1, o); }
        if (t0 > m) {
            float sc = __expf(m - t0);
            acc.x *= sc; acc.y *= sc; acc.z *= sc; acc.w *= sc;
            denom *= sc; m = t0;
        }
        float w0 = __expf(t0 - m);
        denom += w0;
        acc.x = fmaf(w0, a0.x, acc.x); acc.y = fmaf(w0, a0.y, acc.y);
        acc.z = fmaf(w0, a0.z, acc.z); acc.w = fmaf(w0, a0.w, acc.w);
        if (t1 > m) {
            float sc = __expf(m - t1);
            acc.x *= sc; acc.y *= sc; acc.z *= sc; acc.w *= sc;
            denom *= sc; m = t1;
        }
        float w1 = __expf(t1 - m);
        denom += w1;
        acc.x = fmaf(w1, a1.x, acc.x); acc.y = fmaf(w1, a1.y, acc.y);
        acc.z = fmaf(w1, a1.z, acc.z); acc.w = fmaf(w1, a1.w, acc.w);
    }
    if (k < hi) {
        int s0 = csr_src[k];
        float4 a0 = h4f(A2[(size_t)s0 * 16 + gl]);
        float4 v0;
        v0.x = a0.x + xr.x; v0.x = fmaxf(v0.x, NEG_SLOPE * v0.x);
        v0.y = a0.y + xr.y; v0.y = fmaxf(v0.y, NEG_SLOPE * v0.y);
        v0.z = a0.z + xr.z; v0.z = fmaxf(v0.z, NEG_SLOPE * v0.z);
        v0.w = a0.w + xr.w; v0.w = fmaxf(v0.w, NEG_SLOPE * v0.w);
        float t0 = fmaf(v0.x, awv.x, fmaf(v0.y, awv.y, fmaf(v0.z, awv.z, v0.w * awv.w)));
        #pragma unroll
        for (int o = 1; o < 16; o <<= 1) t0 += __shfl_xor(t0, o);
        if (t0 > m) {
            float sc = __expf(m - t0);
            acc.x *= sc; acc.y *= sc; acc.z *= sc; acc.w *= sc;
            denom *= sc; m = t0;
        }
        float w0 = __expf(t0 - m);
        denom += w0;
        acc.x = fmaf(w0, a0.x, acc.x); acc.y = fmaf(w0, a0.y, acc.y);
        acc.z = fmaf(w0, a0.z, acc.z); acc.w = fmaf(w0, a0.w, acc.w);
    }

    float4 bv = ((const float4*)bias)[gl];
    float inv = 1.0f / denom;
    float4 o4;
    o4.x = acc.x * inv + bv.x;
    o4.y = acc.y * inv + bv.y;
    o4.z = acc.z * inv + bv.z;
    o4.w = acc.w * inv + bv.w;
    if (TANH) {
        o4.x = tanhf(o4.x); o4.y = tanhf(o4.y); o4.z = tanhf(o4.z); o4.w = tanhf(o4.w);
    }
    ((float4*)out)[(size_t)d * 16 + gl] = o4;
}

// layer-2 transforms, LDS-tiled: block = 512 threads (8 waves) x 64 nodes.
// wave w computes channels [w*8, w*8+8) for 64 nodes (lane = node). fp16 output.
__global__ __launch_bounds__(512) void k_xfrm2(
        const float* __restrict__ H,
        const float* __restrict__ Wl, const float* __restrict__ bl,
        const float* __restrict__ Wr, const float* __restrict__ br,
        __half* __restrict__ A, __half* __restrict__ B, int N) {
    __shared__ float wls[4096];       // [kk][c]
    __shared__ float wrs[4096];
    __shared__ float hst[64 * 66];    // transposed: [kk][node], pad 66
    int t = threadIdx.x;
    int base = blockIdx.x * 64;

    ((float4*)wls)[t * 2]     = ((const float4*)Wl)[t * 2];
    ((float4*)wls)[t * 2 + 1] = ((const float4*)Wl)[t * 2 + 1];
    ((float4*)wrs)[t * 2]     = ((const float4*)Wr)[t * 2];
    ((float4*)wrs)[t * 2 + 1] = ((const float4*)Wr)[t * 2 + 1];

    #pragma unroll
    for (int u = 0; u < 2; ++u) {
        int j = t * 2 + u;
        int nd = j >> 4, c4 = j & 15;
        int node = base + nd;
        float4 hv = (node < N) ? ((const float4*)H)[(size_t)node * 16 + c4]
                               : make_float4(0.f, 0.f, 0.f, 0.f);
        hst[(c4 * 4 + 0) * 66 + nd] = hv.x;
        hst[(c4 * 4 + 1) * 66 + nd] = hv.y;
        hst[(c4 * 4 + 2) * 66 + nd] = hv.z;
        hst[(c4 * 4 + 3) * 66 + nd] = hv.w;
    }
    __syncthreads();

    int w = t >> 6, l = t & 63;
    float acL[8] = {0, 0, 0, 0, 0, 0, 0, 0};
    float acR[8] = {0, 0, 0, 0, 0, 0, 0, 0};
    #pragma unroll 4
    for (int kk = 0; kk < 64; ++kk) {
        float hv = hst[kk * 66 + l];
        const float4* wl4 = (const float4*)&wls[kk * 64 + w * 8];
        const float4* wr4 = (const float4*)&wrs[kk * 64 + w * 8];
        float4 w0 = wl4[0], w1 = wl4[1];
        float4 r0 = wr4[0], r1 = wr4[1];
        acL[0] = fmaf(hv, w0.x, acL[0]); acL[1] = fmaf(hv, w0.y, acL[1]);
        acL[2] = fmaf(hv, w0.z, acL[2]); acL[3] = fmaf(hv, w0.w, acL[3]);
        acL[4] = fmaf(hv, w1.x, acL[4]); acL[5] = fmaf(hv, w1.y, acL[5]);
        acL[6] = fmaf(hv, w1.z, acL[6]); acL[7] = fmaf(hv, w1.w, acL[7]);
        acR[0] = fmaf(hv, r0.x, acR[0]); acR[1] = fmaf(hv, r0.y, acR[1]);
        acR[2] = fmaf(hv, r0.z, acR[2]); acR[3] = fmaf(hv, r0.w, acR[3]);
        acR[4] = fmaf(hv, r1.x, acR[4]); acR[5] = fmaf(hv, r1.y, acR[5]);
        acR[6] = fmaf(hv, r1.z, acR[6]); acR[7] = fmaf(hv, r1.w, acR[7]);
    }

    int node = base + l;
    if (node < N) {
        float4 bl0 = ((const float4*)bl)[w * 2], bl1 = ((const float4*)bl)[w * 2 + 1];
        float4 br0 = ((const float4*)br)[w * 2], br1 = ((const float4*)br)[w * 2 + 1];
        __half2* A2 = (__half2*)A;
        __half2* B2 = (__half2*)B;
        size_t bo = (size_t)node * 32 + w * 4;
        A2[bo + 0] = __floats2half2_rn(acL[0] + bl0.x, acL[1] + bl0.y);
        A2[bo + 1] = __floats2half2_rn(acL[2] + bl0.z, acL[3] + bl0.w);
        A2[bo + 2] = __floats2half2_rn(acL[4] + bl1.x, acL[5] + bl1.y);
        A2[bo + 3] = __floats2half2_rn(acL[6] + bl1.z, acL[7] + bl1.w);
        B2[bo + 0] = __floats2half2_rn(acR[0] + br0.x, acR[1] + br0.y);
        B2[bo + 1] = __floats2half2_rn(acR[2] + br0.z, acR[3] + br0.w);
        B2[bo + 2] = __floats2half2_rn(acR[4] + br1.x, acR[5] + br1.y);
        B2[bo + 3] = __floats2half2_rn(acR[6] + br1.z, acR[7] + br1.w);
    }
}

__global__ void k_gbounds(const int* __restrict__ batch, int* __restrict__ gstart,
                          int* __restrict__ gend, int N) {
    int i = blockIdx.x * blockDim.x + threadIdx.x;
    if (i >= N) return;
    int g = batch[i];
    if (i == 0 || batch[i - 1] != g) gstart[g] = i;
    if (i == N - 1 || batch[i + 1] != g) gend[g] = i + 1;
}

__global__ void k_pool_seg(const float* __restrict__ C, const float* __restrict__ b2,
                           const int* __restrict__ gstart, const int* __restrict__ gend,
                           float* __restrict__ gout, int G) {
    int w = (int)((blockIdx.x * (size_t)blockDim.x + threadIdx.x) >> 6);
    int lane = threadIdx.x & 63;
    if (w >= G) return;
    float acc = -INFINITY;
    int lo = gstart[w], hi = gend[w];
    for (int i = lo; i < hi; ++i) acc = fmaxf(acc, C[(size_t)i * HID + lane]);
    gout[(size_t)w * HID + lane] = acc + b2[lane];
}

__global__ void k_final(const float* __restrict__ gout, const float* __restrict__ W3,
                        const float* __restrict__ b3, float* __restrict__ out, int G) {
    int idx = blockIdx.x * blockDim.x + threadIdx.x;
    if (idx >= G * 2) return;
    int gi = idx >> 1, j = idx & 1;
    float sum = b3[j];
    #pragma unroll 8
    for (int kk = 0; kk < HID; ++kk) sum += gout[(size_t)gi * HID + kk] * W3[kk * 2 + j];
    out[idx] = sum;
}

extern "C" void kernel_launch(void* const* d_in, const int* in_sizes, int n_in,
                              void* d_out, int out_size, void* d_ws, size_t ws_size,
                              hipStream_t stream) {
    const float* x     = (const float*)d_in[0];
    const int*   ei    = (const int*)d_in[1];
    const int*   batch = (const int*)d_in[2];
    const float* Wl1 = (const float*)d_in[3];
    const float* bl1 = (const float*)d_in[4];
    const float* Wr1 = (const float*)d_in[5];
    const float* br1 = (const float*)d_in[6];
    const float* a1  = (const float*)d_in[7];
    const float* b1  = (const float*)d_in[8];
    const float* Wl2 = (const float*)d_in[9];
    const float* bl2 = (const float*)d_in[10];
    const float* Wr2 = (const float*)d_in[11];
    const float* br2 = (const float*)d_in[12];
    const float* a2  = (const float*)d_in[13];
    const float* b2  = (const float*)d_in[14];
    const float* W3  = (const float*)d_in[15];
    const float* b3  = (const float*)d_in[16];

    const int N = in_sizes[0];          // 100000
    const int E = in_sizes[1] / 2;      // 1600000
    const int G = out_size / 2;         // 1000
    const int NB = (N + 255) >> 8;
    const int NBLK = (E + BLK_E - 1) / BLK_E;

    // ---- workspace layout ----
    float* ws = (float*)d_ws;
    size_t off = 0;
    float*  C  = ws + off; off += (size_t)N * HID;          // sort temporaries overlay here
    __half* Ah = (__half*)(ws + off); off += (size_t)N * HID / 2;
    __half* Bh = (__half*)(ws + off); off += (size_t)N * HID / 2;
    int*   row_off = (int*)(ws + off); off += N + 1;
    int*   csr_src = (int*)(ws + off); off += E;
    float* deg_in  = ws + off; off += N;
    float* deg_out = ws + off; off += N;
    int*   bsS  = (int*)(ws + off); off += NB + 1;
    int*   bsD  = (int*)(ws + off); off += NB + 1;
    int*   totS = (int*)(ws + off); off += NB;
    int*   totD = (int*)(ws + off); off += NB;
    int*   gstart = (int*)(ws + off); off += G;
    int*   gend   = (int*)(ws + off); off += G;
    float* gout   = ws + off; off += (size_t)G * HID;

    unsigned* packD = (unsigned*)C;
    unsigned* packS = packD + E;
    int* histS = (int*)(packS + E);
    int* histD = histS + (size_t)NB * NBLK;

    const int* src  = ei;
    const int* dstp = ei + E;

    const int BT = 256;
    dim3 blk(BT);
    int grid_nodeC = (N * HID + BT - 1) / BT;
    int grid_g16   = (int)(((size_t)N * 16 + BT - 1) / BT);
    int grid_x2    = (N + 63) / 64;

    // ---- CSR build via counting sort (no global atomics) ----
    k_hist2<<<NBLK, 1024, 0, stream>>>(src, dstp, histS, histD, E, NB, NBLK);
    k_binscan<<<2 * NB, 256, 0, stream>>>(histS, histD, totS, totD, NB, NBLK);
    k_binoffset<<<1, 512, 0, stream>>>(totS, totD, bsS, bsD, NB, E, row_off, N);
    k_scatter_bins<<<NBLK, 1024, 0, stream>>>(src, dstp, histS, histD, bsS, bsD,
                                              packS, packD, E, NB, NBLK);
    k_csr_bin<<<NB, 1024, 0, stream>>>(packD, bsD, row_off, deg_in, csr_src, N);
    k_cnt_bin<<<NB, 1024, 0, stream>>>(packS, bsS, deg_out, N);

    hipMemsetAsync(gstart, 0, 2 * (size_t)G * sizeof(int), stream);
    k_gbounds<<<(N + BT - 1) / BT, blk, 0, stream>>>(batch, gstart, gend, N);

    // ---- layer 1 ----
    k_xfrm1<<<grid_nodeC, blk, 0, stream>>>(x, deg_in, deg_out, Wl1, bl1, Wr1, br1, Ah, Bh, N);
    k_gat_fused<true><<<grid_g16, blk, 0, stream>>>(csr_src, row_off, Ah, Bh, a1, b1, C, N);

    // ---- layer 2 ----
    k_xfrm2<<<grid_x2, 512, 0, stream>>>(C, Wl2, bl2, Wr2, br2, Ah, Bh, N);
    k_gat_fused<false><<<grid_g16, blk, 0, stream>>>(csr_src, row_off, Ah, Bh, a2, b2, C, N);

    // ---- pool + final linear ----
    k_pool_seg<<<(G * 64 + BT - 1) / BT, blk, 0, stream>>>(C, b2, gstart, gend, gout, G);
    k_final<<<(G * 2 + BT - 1) / BT, blk, 0, stream>>>(gout, W3, b3, (float*)d_out, G);
}

// Round 8
// 246.017 us; speedup vs baseline: 7.7236x; 1.0046x over previous
//
#include <hip/hip_runtime.h>
#include <hip/hip_bf16.h>
#include <hip/hip_fp16.h>

#define HID 64
#define NEG_SLOPE 0.2f
#define BLK_E 8192        // edges per block in binning passes
#define EDGE_CAP 6144     // LDS edge cache per bin
#define NDB 16            // blocks for degree sort

typedef _Float16 f16x2 __attribute__((ext_vector_type(2)));

// ============ counting-sort CSR build (no global atomics) ============

__global__ void k_hist2(const int* __restrict__ src, const int* __restrict__ dst,
                        int* __restrict__ histS, int* __restrict__ histD,
                        int E, int NB, int NBLK) {
    __shared__ int hs[512], hd[512];
    int t = threadIdx.x, blk = blockIdx.x;
    for (int b = t; b < NB; b += 1024) { hs[b] = 0; hd[b] = 0; }
    __syncthreads();
    int base = blk * BLK_E;
    #pragma unroll
    for (int k = 0; k < BLK_E / 1024; ++k) {
        int i = base + k * 1024 + t;
        if (i < E) {
            atomicAdd(&hs[src[i] >> 8], 1);
            atomicAdd(&hd[dst[i] >> 8], 1);
        }
    }
    __syncthreads();
    for (int b = t; b < NB; b += 1024) {
        histS[b * NBLK + blk] = hs[b];
        histD[b * NBLK + blk] = hd[b];
    }
}

__global__ void k_binscan(int* __restrict__ histS, int* __restrict__ histD,
                          int* __restrict__ totS, int* __restrict__ totD,
                          int NB, int NBLK) {
    __shared__ int s[256];
    int b = blockIdx.x;
    int* hist = histS; int* tot = totS;
    if (b >= NB) { b -= NB; hist = histD; tot = totD; }
    int t = threadIdx.x;
    int v = (t < NBLK) ? hist[b * NBLK + t] : 0;
    s[t] = v;
    __syncthreads();
    for (int o = 1; o < 256; o <<= 1) {
        int u = (t >= o) ? s[t - o] : 0;
        __syncthreads();
        s[t] += u;
        __syncthreads();
    }
    if (t < NBLK) hist[b * NBLK + t] = s[t] - v;
    if (t == 255) tot[b] = s[255];
}

__global__ void k_binoffset(const int* __restrict__ totS, const int* __restrict__ totD,
                            int* __restrict__ bsS, int* __restrict__ bsD,
                            int NB, int E, int* __restrict__ row_off, int N) {
    __shared__ int s[512];
    int t = threadIdx.x;
    int v = (t < NB) ? totS[t] : 0;
    s[t] = v; __syncthreads();
    for (int o = 1; o < 512; o <<= 1) {
        int u = (t >= o) ? s[t - o] : 0;
        __syncthreads(); s[t] += u; __syncthreads();
    }
    if (t < NB) bsS[t] = s[t] - v;
    if (t == 0) bsS[NB] = E;
    __syncthreads();
    v = (t < NB) ? totD[t] : 0;
    s[t] = v; __syncthreads();
    for (int o = 1; o < 512; o <<= 1) {
        int u = (t >= o) ? s[t - o] : 0;
        __syncthreads(); s[t] += u; __syncthreads();
    }
    if (t < NB) bsD[t] = s[t] - v;
    if (t == 0) { bsD[NB] = E; row_off[N] = E; }
}

__global__ void k_scatter_bins(const int* __restrict__ src, const int* __restrict__ dst,
                               const int* __restrict__ histS, const int* __restrict__ histD,
                               const int* __restrict__ bsS, const int* __restrict__ bsD,
                               unsigned* __restrict__ packS, unsigned* __restrict__ packD,
                               int E, int NB, int NBLK) {
    __shared__ int baseS[512], baseD[512];
    int t = threadIdx.x, blk = blockIdx.x;
    for (int b = t; b < NB; b += 1024) {
        baseS[b] = bsS[b] + histS[b * NBLK + blk];
        baseD[b] = bsD[b] + histD[b * NBLK + blk];
    }
    __syncthreads();
    int base = blk * BLK_E;
    #pragma unroll
    for (int k = 0; k < BLK_E / 1024; ++k) {
        int i = base + k * 1024 + t;
        if (i < E) {
            int sv = src[i], dv = dst[i];
            int pD = atomicAdd(&baseD[dv >> 8], 1);
            packD[pD] = ((unsigned)(dv & 255) << 24) | (unsigned)sv;
            int pS = atomicAdd(&baseS[sv >> 8], 1);
            packS[pS] = (unsigned)(sv & 255);
        }
    }
}

__global__ void k_csr_bin(const unsigned* __restrict__ packD, const int* __restrict__ bsD,
                          int* __restrict__ row_off, float* __restrict__ deg_in,
                          int* __restrict__ csr_src, int N) {
    __shared__ int cnt[256], off[256], cur[256];
    __shared__ unsigned eb[EDGE_CAP];
    int b = blockIdx.x, t = threadIdx.x;
    int lo = bsD[b], hi = bsD[b + 1], ne = hi - lo;
    bool fits = (ne <= EDGE_CAP);
    if (t < 256) cnt[t] = 0;
    __syncthreads();
    for (int i = t; i < ne; i += 1024) {
        unsigned v = packD[lo + i];
        if (fits) eb[i] = v;
        atomicAdd(&cnt[v >> 24], 1);
    }
    __syncthreads();
    if (t < 256) off[t] = cnt[t];
    __syncthreads();
    for (int o = 1; o < 256; o <<= 1) {
        int u = 0;
        if (t < 256 && t >= o) u = off[t - o];
        __syncthreads();
        if (t < 256) off[t] += u;
        __syncthreads();
    }
    if (t < 256) {
        int ex = off[t] - cnt[t];
        cur[t] = lo + ex;
        int node = b * 256 + t;
        if (node < N) {
            row_off[node] = lo + ex;
            deg_in[node] = (float)cnt[t];
        }
    }
    __syncthreads();
    for (int i = t; i < ne; i += 1024) {
        unsigned v = fits ? eb[i] : packD[lo + i];
        int pos = atomicAdd(&cur[v >> 24], 1);
        csr_src[pos] = (int)(v & 0xFFFFFFu);
    }
}

__global__ void k_cnt_bin(const unsigned* __restrict__ packS, const int* __restrict__ bsS,
                          float* __restrict__ deg_out, int N) {
    __shared__ int cnt[256];
    int b = blockIdx.x, t = threadIdx.x;
    int lo = bsS[b], hi = bsS[b + 1];
    if (t < 256) cnt[t] = 0;
    __syncthreads();
    for (int i = lo + t; i < hi; i += 1024) atomicAdd(&cnt[packS[i] & 255], 1);
    __syncthreads();
    if (t < 256) {
        int node = b * 256 + t;
        if (node < N) deg_out[node] = (float)cnt[t];
    }
}

// ============ degree sort (perm only changes scheduling, not any FP result) ============

__global__ void k_deghist(const float* __restrict__ deg_in, int* __restrict__ dhist, int N) {
    __shared__ int h[64];
    int t = threadIdx.x, b = blockIdx.x;
    if (t < 64) h[t] = 0;
    __syncthreads();
    int chunk = (N + NDB - 1) / NDB;
    int lo = b * chunk, hi = lo + chunk; if (hi > N) hi = N;
    for (int i = lo + t; i < hi; i += 1024) {
        int dg = (int)deg_in[i]; if (dg > 63) dg = 63;
        atomicAdd(&h[dg], 1);
    }
    __syncthreads();
    if (t < 64) dhist[t * NDB + b] = h[t];
}

__global__ void k_degscan(int* __restrict__ dhist) {
    __shared__ int s[1024];
    int t = threadIdx.x;
    int v = dhist[t];
    s[t] = v; __syncthreads();
    for (int o = 1; o < 1024; o <<= 1) {
        int u = (t >= o) ? s[t - o] : 0;
        __syncthreads(); s[t] += u; __syncthreads();
    }
    dhist[t] = s[t] - v;
}

__global__ void k_degscatter(const float* __restrict__ deg_in, const int* __restrict__ dhist,
                             int* __restrict__ perm, int N) {
    __shared__ int cur[64];
    int t = threadIdx.x, b = blockIdx.x;
    if (t < 64) cur[t] = dhist[t * NDB + b];
    __syncthreads();
    int chunk = (N + NDB - 1) / NDB;
    int lo = b * chunk, hi = lo + chunk; if (hi > N) hi = N;
    for (int i = lo + t; i < hi; i += 1024) {
        int dg = (int)deg_in[i]; if (dg > 63) dg = 63;
        int p = atomicAdd(&cur[dg], 1);
        perm[p] = i;
    }
}

// ============ model kernels ============

__global__ void k_xfrm1(const float* __restrict__ x, const float* __restrict__ deg_in,
                        const float* __restrict__ deg_out,
                        const float* __restrict__ Wl, const float* __restrict__ bl,
                        const float* __restrict__ Wr, const float* __restrict__ br,
                        __half* __restrict__ A, __half* __restrict__ B, int N) {
    int idx = blockIdx.x * blockDim.x + threadIdx.x;
    if (idx >= N * HID) return;
    int n = idx >> 6, c = idx & 63;
    float h0 = x[n], h1 = deg_in[n], h2 = deg_out[n];
    A[idx] = __float2half(h0 * Wl[c] + h1 * Wl[HID + c] + h2 * Wl[2 * HID + c] + bl[c]);
    B[idx] = __float2half(h0 * Wr[c] + h1 * Wr[HID + c] + h2 * Wr[2 * HID + c] + br[c]);
}

struct H8 { f16x2 h[8]; };

__device__ __forceinline__ f16x2 bch2(unsigned u) {
    return __builtin_bit_cast(f16x2, u);
}

__device__ __forceinline__ H8 ldrow(const uint4* __restrict__ T, size_t base) {
    uint4 r0 = T[base], r1 = T[base + 1];
    H8 o;
    o.h[0] = bch2(r0.x); o.h[1] = bch2(r0.y); o.h[2] = bch2(r0.z); o.h[3] = bch2(r0.w);
    o.h[4] = bch2(r1.x); o.h[5] = bch2(r1.y); o.h[6] = bch2(r1.z); o.h[7] = bch2(r1.w);
    return o;
}

// 16-channel partial logit: a^T leakyrelu(a_row + xr), pk-f16 math + fp32 dot
__device__ __forceinline__ float logit16(const H8& a, const H8& x,
                                         const float* __restrict__ awf, f16x2 ns2) {
    float t = 0.0f;
    #pragma unroll
    for (int j = 0; j < 8; ++j) {
        f16x2 s = a.h[j] + x.h[j];
        f16x2 l = __builtin_elementwise_max(s, ns2 * s);
        t = fmaf((float)l.x, awf[2 * j], t);
        t = fmaf((float)l.y, awf[2 * j + 1], t);
    }
    return t;
}

__device__ __forceinline__ void accum16(float* __restrict__ acc, const H8& a, float w) {
    #pragma unroll
    for (int j = 0; j < 8; ++j) {
        acc[2 * j]     = fmaf((float)a.h[j].x, w, acc[2 * j]);
        acc[2 * j + 1] = fmaf((float)a.h[j].y, w, acc[2 * j + 1]);
    }
}

// Fused GATv2 layer: 4 lanes per dst node (16 ch each), degree-sorted order,
// online softmax, no atomics.
template <bool TANH>
__global__ void k_gat_fused(const int* __restrict__ csr_src, const int* __restrict__ row_off,
                            const int* __restrict__ perm,
                            const __half* __restrict__ Ah, const __half* __restrict__ Bh,
                            const float* __restrict__ aw, const float* __restrict__ bias,
                            float* __restrict__ out, int N) {
    int tid = blockIdx.x * blockDim.x + threadIdx.x;
    int r = tid >> 2;
    int gl = threadIdx.x & 3;
    if (r >= N) return;
    int d = perm[r];

    const uint4* A16 = (const uint4*)Ah;
    const uint4* B16 = (const uint4*)Bh;
    f16x2 ns2;
    ns2.x = (_Float16)NEG_SLOPE; ns2.y = (_Float16)NEG_SLOPE;

    float awf[16];
    {
        const float4* a4 = (const float4*)aw;
        #pragma unroll
        for (int j = 0; j < 4; ++j) {
            float4 v = a4[gl * 4 + j];
            awf[4 * j] = v.x; awf[4 * j + 1] = v.y; awf[4 * j + 2] = v.z; awf[4 * j + 3] = v.w;
        }
    }

    size_t rowbase = (size_t)d * 8 + gl * 2;
    H8 xh = ldrow(B16, rowbase);
    H8 as = ldrow(A16, rowbase);

    // self loop seeds online-softmax state
    float t = logit16(as, xh, awf, ns2);
    t += __shfl_xor(t, 1); t += __shfl_xor(t, 2);
    float m = t, denom = 1.0f;
    float acc[16];
    #pragma unroll
    for (int j = 0; j < 8; ++j) {
        acc[2 * j] = (float)as.h[j].x;
        acc[2 * j + 1] = (float)as.h[j].y;
    }

    int lo = row_off[d], hi = row_off[d + 1];
    int k = lo;
    for (; k + 1 < hi; k += 2) {
        int s0 = csr_src[k], s1 = csr_src[k + 1];
        H8 a0 = ldrow(A16, (size_t)s0 * 8 + gl * 2);
        H8 a1 = ldrow(A16, (size_t)s1 * 8 + gl * 2);
        float t0 = logit16(a0, xh, awf, ns2);
        float t1 = logit16(a1, xh, awf, ns2);
        t0 += __shfl_xor(t0, 1); t1 += __shfl_xor(t1, 1);
        t0 += __shfl_xor(t0, 2); t1 += __shfl_xor(t1, 2);
        float mx = fmaxf(t0, t1);
        if (mx > m) {
            float sc = __expf(m - mx);
            denom *= sc;
            #pragma unroll
            for (int j = 0; j < 16; ++j) acc[j] *= sc;
            m = mx;
        }
        float w0 = __expf(t0 - m), w1 = __expf(t1 - m);
        denom += w0 + w1;
        accum16(acc, a0, w0);
        accum16(acc, a1, w1);
    }
    if (k < hi) {
        int s0 = csr_src[k];
        H8 a0 = ldrow(A16, (size_t)s0 * 8 + gl * 2);
        float t0 = logit16(a0, xh, awf, ns2);
        t0 += __shfl_xor(t0, 1); t0 += __shfl_xor(t0, 2);
        if (t0 > m) {
            float sc = __expf(m - t0);
            denom *= sc;
            #pragma unroll
            for (int j = 0; j < 16; ++j) acc[j] *= sc;
            m = t0;
        }
        float w0 = __expf(t0 - m);
        denom += w0;
        accum16(acc, a0, w0);
    }

    float inv = 1.0f / denom;
    const float4* b4 = (const float4*)bias;
    float4* o4 = (float4*)out;
    #pragma unroll
    for (int j = 0; j < 4; ++j) {
        float4 bv = b4[gl * 4 + j];
        float4 o;
        o.x = acc[4 * j] * inv + bv.x;
        o.y = acc[4 * j + 1] * inv + bv.y;
        o.z = acc[4 * j + 2] * inv + bv.z;
        o.w = acc[4 * j + 3] * inv + bv.w;
        if (TANH) { o.x = tanhf(o.x); o.y = tanhf(o.y); o.z = tanhf(o.z); o.w = tanhf(o.w); }
        o4[(size_t)d * 16 + gl * 4 + j] = o;
    }
}

// layer-2 transforms, LDS-tiled: block = 512 threads (8 waves) x 64 nodes. fp16 output.
__global__ __launch_bounds__(512) void k_xfrm2(
        const float* __restrict__ H,
        const float* __restrict__ Wl, const float* __restrict__ bl,
        const float* __restrict__ Wr, const float* __restrict__ br,
        __half* __restrict__ A, __half* __restrict__ B, int N) {
    __shared__ float wls[4096];       // [kk][c]
    __shared__ float wrs[4096];
    __shared__ float hst[64 * 66];    // transposed: [kk][node], pad 66
    int t = threadIdx.x;
    int base = blockIdx.x * 64;

    ((float4*)wls)[t * 2]     = ((const float4*)Wl)[t * 2];
    ((float4*)wls)[t * 2 + 1] = ((const float4*)Wl)[t * 2 + 1];
    ((float4*)wrs)[t * 2]     = ((const float4*)Wr)[t * 2];
    ((float4*)wrs)[t * 2 + 1] = ((const float4*)Wr)[t * 2 + 1];

    #pragma unroll
    for (int u = 0; u < 2; ++u) {
        int j = t * 2 + u;
        int nd = j >> 4, c4 = j & 15;
        int node = base + nd;
        float4 hv = (node < N) ? ((const float4*)H)[(size_t)node * 16 + c4]
                               : make_float4(0.f, 0.f, 0.f, 0.f);
        hst[(c4 * 4 + 0) * 66 + nd] = hv.x;
        hst[(c4 * 4 + 1) * 66 + nd] = hv.y;
        hst[(c4 * 4 + 2) * 66 + nd] = hv.z;
        hst[(c4 * 4 + 3) * 66 + nd] = hv.w;
    }
    __syncthreads();

    int w = t >> 6, l = t & 63;
    float acL[8] = {0, 0, 0, 0, 0, 0, 0, 0};
    float acR[8] = {0, 0, 0, 0, 0, 0, 0, 0};
    #pragma unroll 4
    for (int kk = 0; kk < 64; ++kk) {
        float hv = hst[kk * 66 + l];
        const float4* wl4 = (const float4*)&wls[kk * 64 + w * 8];
        const float4* wr4 = (const float4*)&wrs[kk * 64 + w * 8];
        float4 w0 = wl4[0], w1 = wl4[1];
        float4 r0 = wr4[0], r1 = wr4[1];
        acL[0] = fmaf(hv, w0.x, acL[0]); acL[1] = fmaf(hv, w0.y, acL[1]);
        acL[2] = fmaf(hv, w0.z, acL[2]); acL[3] = fmaf(hv, w0.w, acL[3]);
        acL[4] = fmaf(hv, w1.x, acL[4]); acL[5] = fmaf(hv, w1.y, acL[5]);
        acL[6] = fmaf(hv, w1.z, acL[6]); acL[7] = fmaf(hv, w1.w, acL[7]);
        acR[0] = fmaf(hv, r0.x, acR[0]); acR[1] = fmaf(hv, r0.y, acR[1]);
        acR[2] = fmaf(hv, r0.z, acR[2]); acR[3] = fmaf(hv, r0.w, acR[3]);
        acR[4] = fmaf(hv, r1.x, acR[4]); acR[5] = fmaf(hv, r1.y, acR[5]);
        acR[6] = fmaf(hv, r1.z, acR[6]); acR[7] = fmaf(hv, r1.w, acR[7]);
    }

    int node = base + l;
    if (node < N) {
        float4 bl0 = ((const float4*)bl)[w * 2], bl1 = ((const float4*)bl)[w * 2 + 1];
        float4 br0 = ((const float4*)br)[w * 2], br1 = ((const float4*)br)[w * 2 + 1];
        __half2* A2 = (__half2*)A;
        __half2* B2 = (__half2*)B;
        size_t bo = (size_t)node * 32 + w * 4;
        A2[bo + 0] = __floats2half2_rn(acL[0] + bl0.x, acL[1] + bl0.y);
        A2[bo + 1] = __floats2half2_rn(acL[2] + bl0.z, acL[3] + bl0.w);
        A2[bo + 2] = __floats2half2_rn(acL[4] + bl1.x, acL[5] + bl1.y);
        A2[bo + 3] = __floats2half2_rn(acL[6] + bl1.z, acL[7] + bl1.w);
        B2[bo + 0] = __floats2half2_rn(acR[0] + br0.x, acR[1] + br0.y);
        B2[bo + 1] = __floats2half2_rn(acR[2] + br0.z, acR[3] + br0.w);
        B2[bo + 2] = __floats2half2_rn(acR[4] + br1.x, acR[5] + br1.y);
        B2[bo + 3] = __floats2half2_rn(acR[6] + br1.z, acR[7] + br1.w);
    }
}

__global__ void k_gbounds(const int* __restrict__ batch, int* __restrict__ gstart,
                          int* __restrict__ gend, int N) {
    int i = blockIdx.x * blockDim.x + threadIdx.x;
    if (i >= N) return;
    int g = batch[i];
    if (i == 0 || batch[i - 1] != g) gstart[g] = i;
    if (i == N - 1 || batch[i + 1] != g) gend[g] = i + 1;
}

__global__ void k_pool_seg(const float* __restrict__ C, const float* __restrict__ b2,
                           const int* __restrict__ gstart, const int* __restrict__ gend,
                           float* __restrict__ gout, int G) {
    int w = (int)((blockIdx.x * (size_t)blockDim.x + threadIdx.x) >> 6);
    int lane = threadIdx.x & 63;
    if (w >= G) return;
    float acc = -INFINITY;
    int lo = gstart[w], hi = gend[w];
    for (int i = lo; i < hi; ++i) acc = fmaxf(acc, C[(size_t)i * HID + lane]);
    gout[(size_t)w * HID + lane] = acc + b2[lane];
}

__global__ void k_final(const float* __restrict__ gout, const float* __restrict__ W3,
                        const float* __restrict__ b3, float* __restrict__ out, int G) {
    int idx = blockIdx.x * blockDim.x + threadIdx.x;
    if (idx >= G * 2) return;
    int gi = idx >> 1, j = idx & 1;
    float sum = b3[j];
    #pragma unroll 8
    for (int kk = 0; kk < HID; ++kk) sum += gout[(size_t)gi * HID + kk] * W3[kk * 2 + j];
    out[idx] = sum;
}

extern "C" void kernel_launch(void* const* d_in, const int* in_sizes, int n_in,
                              void* d_out, int out_size, void* d_ws, size_t ws_size,
                              hipStream_t stream) {
    const float* x     = (const float*)d_in[0];
    const int*   ei    = (const int*)d_in[1];
    const int*   batch = (const int*)d_in[2];
    const float* Wl1 = (const float*)d_in[3];
    const float* bl1 = (const float*)d_in[4];
    const float* Wr1 = (const float*)d_in[5];
    const float* br1 = (const float*)d_in[6];
    const float* a1  = (const float*)d_in[7];
    const float* b1  = (const float*)d_in[8];
    const float* Wl2 = (const float*)d_in[9];
    const float* bl2 = (const float*)d_in[10];
    const float* Wr2 = (const float*)d_in[11];
    const float* br2 = (const float*)d_in[12];
    const float* a2  = (const float*)d_in[13];
    const float* b2  = (const float*)d_in[14];
    const float* W3  = (const float*)d_in[15];
    const float* b3  = (const float*)d_in[16];

    const int N = in_sizes[0];          // 100000
    const int E = in_sizes[1] / 2;      // 1600000
    const int G = out_size / 2;         // 1000
    const int NB = (N + 255) >> 8;
    const int NBLK = (E + BLK_E - 1) / BLK_E;

    // ---- workspace layout ----
    float* ws = (float*)d_ws;
    size_t off = 0;
    float*  C  = ws + off; off += (size_t)N * HID;          // sort temporaries overlay here
    __half* Ah = (__half*)(ws + off); off += (size_t)N * HID / 2;
    __half* Bh = (__half*)(ws + off); off += (size_t)N * HID / 2;
    int*   row_off = (int*)(ws + off); off += N + 1;
    int*   csr_src = (int*)(ws + off); off += E;
    float* deg_in  = ws + off; off += N;
    float* deg_out = ws + off; off += N;
    int*   perm    = (int*)(ws + off); off += N;
    int*   dhist   = (int*)(ws + off); off += 1024;
    int*   bsS  = (int*)(ws + off); off += NB + 1;
    int*   bsD  = (int*)(ws + off); off += NB + 1;
    int*   totS = (int*)(ws + off); off += NB;
    int*   totD = (int*)(ws + off); off += NB;
    int*   gstart = (int*)(ws + off); off += G;
    int*   gend   = (int*)(ws + off); off += G;
    float* gout   = ws + off; off += (size_t)G * HID;

    unsigned* packD = (unsigned*)C;
    unsigned* packS = packD + E;
    int* histS = (int*)(packS + E);
    int* histD = histS + (size_t)NB * NBLK;

    const int* src  = ei;
    const int* dstp = ei + E;

    const int BT = 256;
    dim3 blk(BT);
    int grid_nodeC = (N * HID + BT - 1) / BT;
    int grid_g4    = (int)(((size_t)N * 4 + BT - 1) / BT);
    int grid_x2    = (N + 63) / 64;

    // ---- CSR build via counting sort (no global atomics) ----
    k_hist2<<<NBLK, 1024, 0, stream>>>(src, dstp, histS, histD, E, NB, NBLK);
    k_binscan<<<2 * NB, 256, 0, stream>>>(histS, histD, totS, totD, NB, NBLK);
    k_binoffset<<<1, 512, 0, stream>>>(totS, totD, bsS, bsD, NB, E, row_off, N);
    k_scatter_bins<<<NBLK, 1024, 0, stream>>>(src, dstp, histS, histD, bsS, bsD,
                                              packS, packD, E, NB, NBLK);
    k_csr_bin<<<NB, 1024, 0, stream>>>(packD, bsD, row_off, deg_in, csr_src, N);
    k_cnt_bin<<<NB, 1024, 0, stream>>>(packS, bsS, deg_out, N);

    // ---- degree-sorted node permutation (scheduling only) ----
    k_deghist<<<NDB, 1024, 0, stream>>>(deg_in, dhist, N);
    k_degscan<<<1, 1024, 0, stream>>>(dhist);
    k_degscatter<<<NDB, 1024, 0, stream>>>(deg_in, dhist, perm, N);

    (void)hipMemsetAsync(gstart, 0, 2 * (size_t)G * sizeof(int), stream);
    k_gbounds<<<(N + BT - 1) / BT, blk, 0, stream>>>(batch, gstart, gend, N);

    // ---- layer 1 ----
    k_xfrm1<<<grid_nodeC, blk, 0, stream>>>(x, deg_in, deg_out, Wl1, bl1, Wr1, br1, Ah, Bh, N);
    k_gat_fused<true><<<grid_g4, blk, 0, stream>>>(csr_src, row_off, perm, Ah, Bh, a1, b1, C, N);

    // ---- layer 2 ----
    k_xfrm2<<<grid_x2, 512, 0, stream>>>(C, Wl2, bl2, Wr2, br2, Ah, Bh, N);
    k_gat_fused<false><<<grid_g4, blk, 0, stream>>>(csr_src, row_off, perm, Ah, Bh, a2, b2, C, N);

    // ---- pool + final linear ----
    k_pool_seg<<<(G * 64 + BT - 1) / BT, blk, 0, stream>>>(C, b2, gstart, gend, gout, G);
    k_final<<<(G * 2 + BT - 1) / BT, blk, 0, stream>>>(gout, W3, b3, (float*)d_out, G);
}

// Round 9
// 242.164 us; speedup vs baseline: 7.8465x; 1.0159x over previous
//
#include <hip/hip_runtime.h>
#include <hip/hip_bf16.h>
#include <hip/hip_fp16.h>

#define HID 64
#define NEG_SLOPE 0.2f
#define BLK_E 8192        // edges per block in binning passes
#define EDGE_CAP 6144     // LDS edge cache per bin
#define NDB 16            // blocks for degree sort

typedef _Float16 f16x2 __attribute__((ext_vector_type(2)));

// ============ counting-sort CSR build (no global atomics) ============

__global__ void k_hist2(const int* __restrict__ src, const int* __restrict__ dst,
                        int* __restrict__ histS, int* __restrict__ histD,
                        int E, int NB, int NBLK) {
    __shared__ int hs[512], hd[512];
    int t = threadIdx.x, blk = blockIdx.x;
    for (int b = t; b < NB; b += 1024) { hs[b] = 0; hd[b] = 0; }
    __syncthreads();
    int base = blk * BLK_E;
    #pragma unroll
    for (int k = 0; k < BLK_E / 1024; ++k) {
        int i = base + k * 1024 + t;
        if (i < E) {
            atomicAdd(&hs[src[i] >> 8], 1);
            atomicAdd(&hd[dst[i] >> 8], 1);
        }
    }
    __syncthreads();
    for (int b = t; b < NB; b += 1024) {
        histS[b * NBLK + blk] = hs[b];
        histD[b * NBLK + blk] = hd[b];
    }
}

__global__ void k_binscan(int* __restrict__ histS, int* __restrict__ histD,
                          int* __restrict__ totS, int* __restrict__ totD,
                          int NB, int NBLK) {
    __shared__ int s[256];
    int b = blockIdx.x;
    int* hist = histS; int* tot = totS;
    if (b >= NB) { b -= NB; hist = histD; tot = totD; }
    int t = threadIdx.x;
    int v = (t < NBLK) ? hist[b * NBLK + t] : 0;
    s[t] = v;
    __syncthreads();
    for (int o = 1; o < 256; o <<= 1) {
        int u = (t >= o) ? s[t - o] : 0;
        __syncthreads();
        s[t] += u;
        __syncthreads();
    }
    if (t < NBLK) hist[b * NBLK + t] = s[t] - v;
    if (t == 255) tot[b] = s[255];
}

__global__ void k_binoffset(const int* __restrict__ totS, const int* __restrict__ totD,
                            int* __restrict__ bsS, int* __restrict__ bsD,
                            int NB, int E, int* __restrict__ row_off, int N) {
    __shared__ int s[512];
    int t = threadIdx.x;
    int v = (t < NB) ? totS[t] : 0;
    s[t] = v; __syncthreads();
    for (int o = 1; o < 512; o <<= 1) {
        int u = (t >= o) ? s[t - o] : 0;
        __syncthreads(); s[t] += u; __syncthreads();
    }
    if (t < NB) bsS[t] = s[t] - v;
    if (t == 0) bsS[NB] = E;
    __syncthreads();
    v = (t < NB) ? totD[t] : 0;
    s[t] = v; __syncthreads();
    for (int o = 1; o < 512; o <<= 1) {
        int u = (t >= o) ? s[t - o] : 0;
        __syncthreads(); s[t] += u; __syncthreads();
    }
    if (t < NB) bsD[t] = s[t] - v;
    if (t == 0) { bsD[NB] = E; row_off[N] = E; }
}

__global__ void k_scatter_bins(const int* __restrict__ src, const int* __restrict__ dst,
                               const int* __restrict__ histS, const int* __restrict__ histD,
                               const int* __restrict__ bsS, const int* __restrict__ bsD,
                               unsigned* __restrict__ packS, unsigned* __restrict__ packD,
                               int E, int NB, int NBLK) {
    __shared__ int baseS[512], baseD[512];
    int t = threadIdx.x, blk = blockIdx.x;
    for (int b = t; b < NB; b += 1024) {
        baseS[b] = bsS[b] + histS[b * NBLK + blk];
        baseD[b] = bsD[b] + histD[b * NBLK + blk];
    }
    __syncthreads();
    int base = blk * BLK_E;
    #pragma unroll
    for (int k = 0; k < BLK_E / 1024; ++k) {
        int i = base + k * 1024 + t;
        if (i < E) {
            int sv = src[i], dv = dst[i];
            int pD = atomicAdd(&baseD[dv >> 8], 1);
            packD[pD] = ((unsigned)(dv & 255) << 24) | (unsigned)sv;
            int pS = atomicAdd(&baseS[sv >> 8], 1);
            packS[pS] = (unsigned)(sv & 255);
        }
    }
}

__global__ void k_csr_bin(const unsigned* __restrict__ packD, const int* __restrict__ bsD,
                          int* __restrict__ row_off, float* __restrict__ deg_in,
                          int* __restrict__ csr_src, int N) {
    __shared__ int cnt[256], off[256], cur[256];
    __shared__ unsigned eb[EDGE_CAP];
    int b = blockIdx.x, t = threadIdx.x;
    int lo = bsD[b], hi = bsD[b + 1], ne = hi - lo;
    bool fits = (ne <= EDGE_CAP);
    if (t < 256) cnt[t] = 0;
    __syncthreads();
    for (int i = t; i < ne; i += 1024) {
        unsigned v = packD[lo + i];
        if (fits) eb[i] = v;
        atomicAdd(&cnt[v >> 24], 1);
    }
    __syncthreads();
    if (t < 256) off[t] = cnt[t];
    __syncthreads();
    for (int o = 1; o < 256; o <<= 1) {
        int u = 0;
        if (t < 256 && t >= o) u = off[t - o];
        __syncthreads();
        if (t < 256) off[t] += u;
        __syncthreads();
    }
    if (t < 256) {
        int ex = off[t] - cnt[t];
        cur[t] = lo + ex;
        int node = b * 256 + t;
        if (node < N) {
            row_off[node] = lo + ex;
            deg_in[node] = (float)cnt[t];
        }
    }
    __syncthreads();
    for (int i = t; i < ne; i += 1024) {
        unsigned v = fits ? eb[i] : packD[lo + i];
        int pos = atomicAdd(&cur[v >> 24], 1);
        csr_src[pos] = (int)(v & 0xFFFFFFu);
    }
}

__global__ void k_cnt_bin(const unsigned* __restrict__ packS, const int* __restrict__ bsS,
                          float* __restrict__ deg_out, int N) {
    __shared__ int cnt[256];
    int b = blockIdx.x, t = threadIdx.x;
    int lo = bsS[b], hi = bsS[b + 1];
    if (t < 256) cnt[t] = 0;
    __syncthreads();
    for (int i = lo + t; i < hi; i += 1024) atomicAdd(&cnt[packS[i] & 255], 1);
    __syncthreads();
    if (t < 256) {
        int node = b * 256 + t;
        if (node < N) deg_out[node] = (float)cnt[t];
    }
}

// ============ degree sort (perm only changes scheduling, not any FP result) ============

__global__ void k_deghist(const float* __restrict__ deg_in, int* __restrict__ dhist, int N) {
    __shared__ int h[64];
    int t = threadIdx.x, b = blockIdx.x;
    if (t < 64) h[t] = 0;
    __syncthreads();
    int chunk = (N + NDB - 1) / NDB;
    int lo = b * chunk, hi = lo + chunk; if (hi > N) hi = N;
    for (int i = lo + t; i < hi; i += 1024) {
        int dg = (int)deg_in[i]; if (dg > 63) dg = 63;
        atomicAdd(&h[dg], 1);
    }
    __syncthreads();
    if (t < 64) dhist[t * NDB + b] = h[t];
}

__global__ void k_degscan(int* __restrict__ dhist) {
    __shared__ int s[1024];
    int t = threadIdx.x;
    int v = dhist[t];
    s[t] = v; __syncthreads();
    for (int o = 1; o < 1024; o <<= 1) {
        int u = (t >= o) ? s[t - o] : 0;
        __syncthreads(); s[t] += u; __syncthreads();
    }
    dhist[t] = s[t] - v;
}

__global__ void k_degscatter(const float* __restrict__ deg_in, const int* __restrict__ dhist,
                             int* __restrict__ perm, int N) {
    __shared__ int cur[64];
    int t = threadIdx.x, b = blockIdx.x;
    if (t < 64) cur[t] = dhist[t * NDB + b];
    __syncthreads();
    int chunk = (N + NDB - 1) / NDB;
    int lo = b * chunk, hi = lo + chunk; if (hi > N) hi = N;
    for (int i = lo + t; i < hi; i += 1024) {
        int dg = (int)deg_in[i]; if (dg > 63) dg = 63;
        int p = atomicAdd(&cur[dg], 1);
        perm[p] = i;
    }
}

// ============ model kernels ============

__global__ void k_xfrm1(const float* __restrict__ x, const float* __restrict__ deg_in,
                        const float* __restrict__ deg_out,
                        const float* __restrict__ Wl, const float* __restrict__ bl,
                        const float* __restrict__ Wr, const float* __restrict__ br,
                        __half* __restrict__ A, __half* __restrict__ B, int N) {
    int idx = blockIdx.x * blockDim.x + threadIdx.x;
    if (idx >= N * HID) return;
    int n = idx >> 6, c = idx & 63;
    float h0 = x[n], h1 = deg_in[n], h2 = deg_out[n];
    A[idx] = __float2half(h0 * Wl[c] + h1 * Wl[HID + c] + h2 * Wl[2 * HID + c] + bl[c]);
    B[idx] = __float2half(h0 * Wr[c] + h1 * Wr[HID + c] + h2 * Wr[2 * HID + c] + br[c]);
}

struct H8 { f16x2 h[8]; };

__device__ __forceinline__ f16x2 bch2(unsigned u) {
    return __builtin_bit_cast(f16x2, u);
}

__device__ __forceinline__ H8 ldrow(const uint4* __restrict__ T, size_t base) {
    uint4 r0 = T[base], r1 = T[base + 1];
    H8 o;
    o.h[0] = bch2(r0.x); o.h[1] = bch2(r0.y); o.h[2] = bch2(r0.z); o.h[3] = bch2(r0.w);
    o.h[4] = bch2(r1.x); o.h[5] = bch2(r1.y); o.h[6] = bch2(r1.z); o.h[7] = bch2(r1.w);
    return o;
}

// 16-channel partial logit: a^T leakyrelu(a_row + xr), pk-f16 math + fp32 dot
__device__ __forceinline__ float logit16(const H8& a, const H8& x,
                                         const float* __restrict__ awf, f16x2 ns2) {
    float t = 0.0f;
    #pragma unroll
    for (int j = 0; j < 8; ++j) {
        f16x2 s = a.h[j] + x.h[j];
        f16x2 l = __builtin_elementwise_max(s, ns2 * s);
        t = fmaf((float)l.x, awf[2 * j], t);
        t = fmaf((float)l.y, awf[2 * j + 1], t);
    }
    return t;
}

__device__ __forceinline__ void accum16(float* __restrict__ acc, const H8& a, float w) {
    #pragma unroll
    for (int j = 0; j < 8; ++j) {
        acc[2 * j]     = fmaf((float)a.h[j].x, w, acc[2 * j]);
        acc[2 * j + 1] = fmaf((float)a.h[j].y, w, acc[2 * j + 1]);
    }
}

// Fused GATv2 layer: 4 lanes per dst node (16 ch each), descending-degree order,
// batch-4 edge unroll for MLP, online softmax, no atomics.
template <bool TANH>
__global__ void k_gat_fused(const int* __restrict__ csr_src, const int* __restrict__ row_off,
                            const int* __restrict__ perm,
                            const __half* __restrict__ Ah, const __half* __restrict__ Bh,
                            const float* __restrict__ aw, const float* __restrict__ bias,
                            float* __restrict__ out, int N) {
    int tid = blockIdx.x * blockDim.x + threadIdx.x;
    int r = tid >> 2;
    int gl = threadIdx.x & 3;
    if (r >= N) return;
    int d = perm[N - 1 - r];   // descending degree: heavy rows dispatched first

    const uint4* A16 = (const uint4*)Ah;
    const uint4* B16 = (const uint4*)Bh;
    f16x2 ns2;
    ns2.x = (_Float16)NEG_SLOPE; ns2.y = (_Float16)NEG_SLOPE;

    float awf[16];
    {
        const float4* a4 = (const float4*)aw;
        #pragma unroll
        for (int j = 0; j < 4; ++j) {
            float4 v = a4[gl * 4 + j];
            awf[4 * j] = v.x; awf[4 * j + 1] = v.y; awf[4 * j + 2] = v.z; awf[4 * j + 3] = v.w;
        }
    }

    size_t rowbase = (size_t)d * 8 + gl * 2;
    H8 xh = ldrow(B16, rowbase);
    H8 as = ldrow(A16, rowbase);

    // self loop seeds online-softmax state
    float t = logit16(as, xh, awf, ns2);
    t += __shfl_xor(t, 1); t += __shfl_xor(t, 2);
    float m = t, denom = 1.0f;
    float acc[16];
    #pragma unroll
    for (int j = 0; j < 8; ++j) {
        acc[2 * j] = (float)as.h[j].x;
        acc[2 * j + 1] = (float)as.h[j].y;
    }

    int lo = row_off[d], hi = row_off[d + 1];
    int k = lo;
    // batch-4: 8 row-loads in flight, one rescale check per 4 edges
    for (; k + 3 < hi; k += 4) {
        int s0 = csr_src[k], s1 = csr_src[k + 1], s2 = csr_src[k + 2], s3 = csr_src[k + 3];
        H8 a0 = ldrow(A16, (size_t)s0 * 8 + gl * 2);
        H8 a1 = ldrow(A16, (size_t)s1 * 8 + gl * 2);
        H8 a2 = ldrow(A16, (size_t)s2 * 8 + gl * 2);
        H8 a3 = ldrow(A16, (size_t)s3 * 8 + gl * 2);
        float t0 = logit16(a0, xh, awf, ns2);
        float t1 = logit16(a1, xh, awf, ns2);
        float t2 = logit16(a2, xh, awf, ns2);
        float t3 = logit16(a3, xh, awf, ns2);
        t0 += __shfl_xor(t0, 1); t1 += __shfl_xor(t1, 1);
        t2 += __shfl_xor(t2, 1); t3 += __shfl_xor(t3, 1);
        t0 += __shfl_xor(t0, 2); t1 += __shfl_xor(t1, 2);
        t2 += __shfl_xor(t2, 2); t3 += __shfl_xor(t3, 2);
        float mx = fmaxf(fmaxf(t0, t1), fmaxf(t2, t3));
        if (mx > m) {
            float sc = __expf(m - mx);
            denom *= sc;
            #pragma unroll
            for (int j = 0; j < 16; ++j) acc[j] *= sc;
            m = mx;
        }
        float w0 = __expf(t0 - m), w1 = __expf(t1 - m);
        float w2 = __expf(t2 - m), w3 = __expf(t3 - m);
        denom += (w0 + w1) + (w2 + w3);
        accum16(acc, a0, w0);
        accum16(acc, a1, w1);
        accum16(acc, a2, w2);
        accum16(acc, a3, w3);
    }
    // tail (<=3 edges)
    for (; k < hi; ++k) {
        int s0 = csr_src[k];
        H8 a0 = ldrow(A16, (size_t)s0 * 8 + gl * 2);
        float t0 = logit16(a0, xh, awf, ns2);
        t0 += __shfl_xor(t0, 1); t0 += __shfl_xor(t0, 2);
        if (t0 > m) {
            float sc = __expf(m - t0);
            denom *= sc;
            #pragma unroll
            for (int j = 0; j < 16; ++j) acc[j] *= sc;
            m = t0;
        }
        float w0 = __expf(t0 - m);
        denom += w0;
        accum16(acc, a0, w0);
    }

    float inv = 1.0f / denom;
    const float4* b4 = (const float4*)bias;
    float4* o4 = (float4*)out;
    #pragma unroll
    for (int j = 0; j < 4; ++j) {
        float4 bv = b4[gl * 4 + j];
        float4 o;
        o.x = acc[4 * j] * inv + bv.x;
        o.y = acc[4 * j + 1] * inv + bv.y;
        o.z = acc[4 * j + 2] * inv + bv.z;
        o.w = acc[4 * j + 3] * inv + bv.w;
        if (TANH) { o.x = tanhf(o.x); o.y = tanhf(o.y); o.z = tanhf(o.z); o.w = tanhf(o.w); }
        o4[(size_t)d * 16 + gl * 4 + j] = o;
    }
}

// layer-2 transforms, LDS-tiled: block = 512 threads (8 waves) x 64 nodes. fp16 output.
__global__ __launch_bounds__(512) void k_xfrm2(
        const float* __restrict__ H,
        const float* __restrict__ Wl, const float* __restrict__ bl,
        const float* __restrict__ Wr, const float* __restrict__ br,
        __half* __restrict__ A, __half* __restrict__ B, int N) {
    __shared__ float wls[4096];       // [kk][c]
    __shared__ float wrs[4096];
    __shared__ float hst[64 * 66];    // transposed: [kk][node], pad 66
    int t = threadIdx.x;
    int base = blockIdx.x * 64;

    ((float4*)wls)[t * 2]     = ((const float4*)Wl)[t * 2];
    ((float4*)wls)[t * 2 + 1] = ((const float4*)Wl)[t * 2 + 1];
    ((float4*)wrs)[t * 2]     = ((const float4*)Wr)[t * 2];
    ((float4*)wrs)[t * 2 + 1] = ((const float4*)Wr)[t * 2 + 1];

    #pragma unroll
    for (int u = 0; u < 2; ++u) {
        int j = t * 2 + u;
        int nd = j >> 4, c4 = j & 15;
        int node = base + nd;
        float4 hv = (node < N) ? ((const float4*)H)[(size_t)node * 16 + c4]
                               : make_float4(0.f, 0.f, 0.f, 0.f);
        hst[(c4 * 4 + 0) * 66 + nd] = hv.x;
        hst[(c4 * 4 + 1) * 66 + nd] = hv.y;
        hst[(c4 * 4 + 2) * 66 + nd] = hv.z;
        hst[(c4 * 4 + 3) * 66 + nd] = hv.w;
    }
    __syncthreads();

    int w = t >> 6, l = t & 63;
    float acL[8] = {0, 0, 0, 0, 0, 0, 0, 0};
    float acR[8] = {0, 0, 0, 0, 0, 0, 0, 0};
    #pragma unroll 4
    for (int kk = 0; kk < 64; ++kk) {
        float hv = hst[kk * 66 + l];
        const float4* wl4 = (const float4*)&wls[kk * 64 + w * 8];
        const float4* wr4 = (const float4*)&wrs[kk * 64 + w * 8];
        float4 w0 = wl4[0], w1 = wl4[1];
        float4 r0 = wr4[0], r1 = wr4[1];
        acL[0] = fmaf(hv, w0.x, acL[0]); acL[1] = fmaf(hv, w0.y, acL[1]);
        acL[2] = fmaf(hv, w0.z, acL[2]); acL[3] = fmaf(hv, w0.w, acL[3]);
        acL[4] = fmaf(hv, w1.x, acL[4]); acL[5] = fmaf(hv, w1.y, acL[5]);
        acL[6] = fmaf(hv, w1.z, acL[6]); acL[7] = fmaf(hv, w1.w, acL[7]);
        acR[0] = fmaf(hv, r0.x, acR[0]); acR[1] = fmaf(hv, r0.y, acR[1]);
        acR[2] = fmaf(hv, r0.z, acR[2]); acR[3] = fmaf(hv, r0.w, acR[3]);
        acR[4] = fmaf(hv, r1.x, acR[4]); acR[5] = fmaf(hv, r1.y, acR[5]);
        acR[6] = fmaf(hv, r1.z, acR[6]); acR[7] = fmaf(hv, r1.w, acR[7]);
    }

    int node = base + l;
    if (node < N) {
        float4 bl0 = ((const float4*)bl)[w * 2], bl1 = ((const float4*)bl)[w * 2 + 1];
        float4 br0 = ((const float4*)br)[w * 2], br1 = ((const float4*)br)[w * 2 + 1];
        __half2* A2 = (__half2*)A;
        __half2* B2 = (__half2*)B;
        size_t bo = (size_t)node * 32 + w * 4;
        A2[bo + 0] = __floats2half2_rn(acL[0] + bl0.x, acL[1] + bl0.y);
        A2[bo + 1] = __floats2half2_rn(acL[2] + bl0.z, acL[3] + bl0.w);
        A2[bo + 2] = __floats2half2_rn(acL[4] + bl1.x, acL[5] + bl1.y);
        A2[bo + 3] = __floats2half2_rn(acL[6] + bl1.z, acL[7] + bl1.w);
        B2[bo + 0] = __floats2half2_rn(acR[0] + br0.x, acR[1] + br0.y);
        B2[bo + 1] = __floats2half2_rn(acR[2] + br0.z, acR[3] + br0.w);
        B2[bo + 2] = __floats2half2_rn(acR[4] + br1.x, acR[5] + br1.y);
        B2[bo + 3] = __floats2half2_rn(acR[6] + br1.z, acR[7] + br1.w);
    }
}

__global__ void k_gbounds(const int* __restrict__ batch, int* __restrict__ gstart,
                          int* __restrict__ gend, int N) {
    int i = blockIdx.x * blockDim.x + threadIdx.x;
    if (i >= N) return;
    int g = batch[i];
    if (i == 0 || batch[i - 1] != g) gstart[g] = i;
    if (i == N - 1 || batch[i + 1] != g) gend[g] = i + 1;
}

__global__ void k_pool_seg(const float* __restrict__ C, const float* __restrict__ b2,
                           const int* __restrict__ gstart, const int* __restrict__ gend,
                           float* __restrict__ gout, int G) {
    int w = (int)((blockIdx.x * (size_t)blockDim.x + threadIdx.x) >> 6);
    int lane = threadIdx.x & 63;
    if (w >= G) return;
    float acc = -INFINITY;
    int lo = gstart[w], hi = gend[w];
    for (int i = lo; i < hi; ++i) acc = fmaxf(acc, C[(size_t)i * HID + lane]);
    gout[(size_t)w * HID + lane] = acc + b2[lane];
}

__global__ void k_final(const float* __restrict__ gout, const float* __restrict__ W3,
                        const float* __restrict__ b3, float* __restrict__ out, int G) {
    int idx = blockIdx.x * blockDim.x + threadIdx.x;
    if (idx >= G * 2) return;
    int gi = idx >> 1, j = idx & 1;
    float sum = b3[j];
    #pragma unroll 8
    for (int kk = 0; kk < HID; ++kk) sum += gout[(size_t)gi * HID + kk] * W3[kk * 2 + j];
    out[idx] = sum;
}

extern "C" void kernel_launch(void* const* d_in, const int* in_sizes, int n_in,
                              void* d_out, int out_size, void* d_ws, size_t ws_size,
                              hipStream_t stream) {
    const float* x     = (const float*)d_in[0];
    const int*   ei    = (const int*)d_in[1];
    const int*   batch = (const int*)d_in[2];
    const float* Wl1 = (const float*)d_in[3];
    const float* bl1 = (const float*)d_in[4];
    const float* Wr1 = (const float*)d_in[5];
    const float* br1 = (const float*)d_in[6];
    const float* a1  = (const float*)d_in[7];
    const float* b1  = (const float*)d_in[8];
    const float* Wl2 = (const float*)d_in[9];
    const float* bl2 = (const float*)d_in[10];
    const float* Wr2 = (const float*)d_in[11];
    const float* br2 = (const float*)d_in[12];
    const float* a2  = (const float*)d_in[13];
    const float* b2  = (const float*)d_in[14];
    const float* W3  = (const float*)d_in[15];
    const float* b3  = (const float*)d_in[16];

    const int N = in_sizes[0];          // 100000
    const int E = in_sizes[1] / 2;      // 1600000
    const int G = out_size / 2;         // 1000
    const int NB = (N + 255) >> 8;
    const int NBLK = (E + BLK_E - 1) / BLK_E;

    // ---- workspace layout ----
    float* ws = (float*)d_ws;
    size_t off = 0;
    float*  C  = ws + off; off += (size_t)N * HID;          // sort temporaries overlay here
    __half* Ah = (__half*)(ws + off); off += (size_t)N * HID / 2;
    __half* Bh = (__half*)(ws + off); off += (size_t)N * HID / 2;
    int*   row_off = (int*)(ws + off); off += N + 1;
    int*   csr_src = (int*)(ws + off); off += E;
    float* deg_in  = ws + off; off += N;
    float* deg_out = ws + off; off += N;
    int*   perm    = (int*)(ws + off); off += N;
    int*   dhist   = (int*)(ws + off); off += 1024;
    int*   bsS  = (int*)(ws + off); off += NB + 1;
    int*   bsD  = (int*)(ws + off); off += NB + 1;
    int*   totS = (int*)(ws + off); off += NB;
    int*   totD = (int*)(ws + off); off += NB;
    int*   gstart = (int*)(ws + off); off += G;
    int*   gend   = (int*)(ws + off); off += G;
    float* gout   = ws + off; off += (size_t)G * HID;

    unsigned* packD = (unsigned*)C;
    unsigned* packS = packD + E;
    int* histS = (int*)(packS + E);
    int* histD = histS + (size_t)NB * NBLK;

    const int* src  = ei;
    const int* dstp = ei + E;

    const int BT = 256;
    dim3 blk(BT);
    int grid_nodeC = (N * HID + BT - 1) / BT;
    int grid_g4    = (int)(((size_t)N * 4 + BT - 1) / BT);
    int grid_x2    = (N + 63) / 64;

    // ---- CSR build via counting sort (no global atomics) ----
    k_hist2<<<NBLK, 1024, 0, stream>>>(src, dstp, histS, histD, E, NB, NBLK);
    k_binscan<<<2 * NB, 256, 0, stream>>>(histS, histD, totS, totD, NB, NBLK);
    k_binoffset<<<1, 512, 0, stream>>>(totS, totD, bsS, bsD, NB, E, row_off, N);
    k_scatter_bins<<<NBLK, 1024, 0, stream>>>(src, dstp, histS, histD, bsS, bsD,
                                              packS, packD, E, NB, NBLK);
    k_csr_bin<<<NB, 1024, 0, stream>>>(packD, bsD, row_off, deg_in, csr_src, N);
    k_cnt_bin<<<NB, 1024, 0, stream>>>(packS, bsS, deg_out, N);

    // ---- degree-sorted node permutation (scheduling only) ----
    k_deghist<<<NDB, 1024, 0, stream>>>(deg_in, dhist, N);
    k_degscan<<<1, 1024, 0, stream>>>(dhist);
    k_degscatter<<<NDB, 1024, 0, stream>>>(deg_in, dhist, perm, N);

    (void)hipMemsetAsync(gstart, 0, 2 * (size_t)G * sizeof(int), stream);
    k_gbounds<<<(N + BT - 1) / BT, blk, 0, stream>>>(batch, gstart, gend, N);

    // ---- layer 1 ----
    k_xfrm1<<<grid_nodeC, blk, 0, stream>>>(x, deg_in, deg_out, Wl1, bl1, Wr1, br1, Ah, Bh, N);
    k_gat_fused<true><<<grid_g4, blk, 0, stream>>>(csr_src, row_off, perm, Ah, Bh, a1, b1, C, N);

    // ---- layer 2 ----
    k_xfrm2<<<grid_x2, 512, 0, stream>>>(C, Wl2, bl2, Wr2, br2, Ah, Bh, N);
    k_gat_fused<false><<<grid_g4, blk, 0, stream>>>(csr_src, row_off, perm, Ah, Bh, a2, b2, C, N);

    // ---- pool + final linear ----
    k_pool_seg<<<(G * 64 + BT - 1) / BT, blk, 0, stream>>>(C, b2, gstart, gend, gout, G);
    k_final<<<(G * 2 + BT - 1) / BT, blk, 0, stream>>>(gout, W3, b3, (float*)d_out, G);
}